// Round 1
// baseline (281.743 us; speedup 1.0000x reference)
//
#include <hip/hip_runtime.h>
#include <hip/hip_bf16.h>

// Problem: B=2, T=2048, E=256, S=128, W=8, H=150
// Factorization: pairs@w1 = gi@w1a + gj@w1b + (gi*gj)@w1c  (w1 split in 768-row blocks)
//   u_i = gi@w1a + b1   (256 rows)
//   v_j = gj@w1b        (256 rows)
//   cross_{ij} = (gi*gj)@w1c  (32768 pairs -- the heavy GEMM)
//
// ws layout (floats):
//   attns   [4096]          @ 0
//   g       [256*768]       @ 4096
//   ment    [256]           @ 200704
//   u_pad   [256*192]       @ 200960   (includes pair_b1; zero-padded h>=150)
//   v_pad   [256*192]       @ 250112
//   w1c_pad [768*192]       @ 299264   (pair_w1 rows 1536..2303, zero-padded)
//   w2_pad  [150*192]       @ 446720   (pair_w2, zero-padded)
//   b2_pad  [192]           @ 475520
//   w3_pad  [192]           @ 475712
// total 475904 floats = 1.91 MB

#define DEV_INLINE __device__ __forceinline__

// ---------------- prep: build zero-padded copies of pair weights ----------------
__global__ __launch_bounds__(256) void prep_pads_kernel(
    const float* __restrict__ pw1, const float* __restrict__ pw2,
    const float* __restrict__ pb2, const float* __restrict__ pw3,
    float* __restrict__ w1c_pad, float* __restrict__ w2_pad,
    float* __restrict__ b2_pad, float* __restrict__ w3_pad)
{
    int idx = blockIdx.x * 256 + threadIdx.x;   // grid covers 176640 exactly
    if (idx < 147456) {                          // w1c_pad: 768 x 192
        int e = idx / 192, h = idx % 192;
        w1c_pad[idx] = (h < 150) ? pw1[(1536 + e) * 150 + h] : 0.f;
    } else if (idx < 176256) {                   // w2_pad: 150 x 192
        int j = idx - 147456;
        int k = j / 192, h = j % 192;
        w2_pad[j] = (h < 150) ? pw2[k * 150 + h] : 0.f;
    } else if (idx < 176448) {
        int h = idx - 176256;
        b2_pad[h] = (h < 150) ? pb2[h] : 0.f;
    } else {
        int h = idx - 176448;
        w3_pad[h] = (h < 150) ? pw3[h] : 0.f;
    }
}

// ---------------- generic scalar-output MLP (d_in -> 150 -> 150 -> 1) ----------------
// One wave computes RPW rows. Lane owns h in {lane, lane+64, lane+128 (lane<22)}.
template <int DIN, int RPW>
__global__ __launch_bounds__(256) void mlp_scalar_kernel(
    const float* __restrict__ x,
    const float* __restrict__ w1, const float* __restrict__ b1,
    const float* __restrict__ w2, const float* __restrict__ b2,
    const float* __restrict__ w3, const float* __restrict__ b3,
    float* __restrict__ out)
{
    __shared__ float xs[4][RPW][DIN];
    const int lane = threadIdx.x & 63;
    const int wid  = threadIdx.x >> 6;
    const int rbase = blockIdx.x * (4 * RPW) + wid * RPW;

    for (int idx = lane; idx < RPW * DIN; idx += 64) {
        int r = idx / DIN, e = idx % DIN;
        xs[wid][r][e] = x[(size_t)(rbase + r) * DIN + e];
    }
    __syncthreads();

    const bool l22 = lane < 22;
    const int  h2i = l22 ? (128 + lane) : 0;   // always-in-bounds 3rd h slot

    float a0[RPW], a1[RPW], a2[RPW];
#pragma unroll
    for (int r = 0; r < RPW; ++r) { a0[r] = 0.f; a1[r] = 0.f; a2[r] = 0.f; }

    for (int e = 0; e < DIN; ++e) {
        float w_0 = w1[e * 150 + lane];
        float w_1 = w1[e * 150 + 64 + lane];
        float w_2 = w1[e * 150 + h2i];          // garbage for lane>=22, never used
#pragma unroll
        for (int r = 0; r < RPW; ++r) {
            float xv = xs[wid][r][e];
            a0[r] = fmaf(xv, w_0, a0[r]);
            a1[r] = fmaf(xv, w_1, a1[r]);
            a2[r] = fmaf(xv, w_2, a2[r]);
        }
    }
    float bb0 = b1[lane], bb1 = b1[64 + lane], bb2 = b1[h2i];
#pragma unroll
    for (int r = 0; r < RPW; ++r) {
        a0[r] = fmaxf(a0[r] + bb0, 0.f);
        a1[r] = fmaxf(a1[r] + bb1, 0.f);
        a2[r] = fmaxf(a2[r] + bb2, 0.f);
    }

    float c0[RPW], c1[RPW], c2[RPW];
    float cb0 = b2[lane], cb1 = b2[64 + lane], cb2 = b2[h2i];
#pragma unroll
    for (int r = 0; r < RPW; ++r) { c0[r] = cb0; c1[r] = cb1; c2[r] = cb2; }

    for (int kk = 0; kk < 64; ++kk) {
        float w_0 = w2[kk * 150 + lane];
        float w_1 = w2[kk * 150 + 64 + lane];
        float w_2 = w2[kk * 150 + h2i];
#pragma unroll
        for (int r = 0; r < RPW; ++r) {
            float hv = __shfl(a0[r], kk);
            c0[r] = fmaf(hv, w_0, c0[r]);
            c1[r] = fmaf(hv, w_1, c1[r]);
            c2[r] = fmaf(hv, w_2, c2[r]);
        }
    }
    for (int kk = 0; kk < 64; ++kk) {
        int k = 64 + kk;
        float w_0 = w2[k * 150 + lane];
        float w_1 = w2[k * 150 + 64 + lane];
        float w_2 = w2[k * 150 + h2i];
#pragma unroll
        for (int r = 0; r < RPW; ++r) {
            float hv = __shfl(a1[r], kk);
            c0[r] = fmaf(hv, w_0, c0[r]);
            c1[r] = fmaf(hv, w_1, c1[r]);
            c2[r] = fmaf(hv, w_2, c2[r]);
        }
    }
    for (int kk = 0; kk < 22; ++kk) {
        int k = 128 + kk;
        float w_0 = w2[k * 150 + lane];
        float w_1 = w2[k * 150 + 64 + lane];
        float w_2 = w2[k * 150 + h2i];
#pragma unroll
        for (int r = 0; r < RPW; ++r) {
            float hv = __shfl(a2[r], kk);
            c0[r] = fmaf(hv, w_0, c0[r]);
            c1[r] = fmaf(hv, w_1, c1[r]);
            c2[r] = fmaf(hv, w_2, c2[r]);
        }
    }

    float w30 = w3[lane], w31 = w3[64 + lane], w32 = w3[h2i];
    float b3v = b3[0];
#pragma unroll
    for (int r = 0; r < RPW; ++r) {
        float d0 = fmaxf(c0[r], 0.f);
        float d1 = fmaxf(c1[r], 0.f);
        float d2 = fmaxf(c2[r], 0.f);
        float part = d0 * w30 + d1 * w31 + (l22 ? d2 * w32 : 0.f);
#pragma unroll
        for (int off = 32; off; off >>= 1) part += __shfl_xor(part, off);
        if (lane == 0) out[rbase + r] = part + b3v;
    }
}

// ---------------- build g = [start, end, weighted] ----------------
__global__ __launch_bounds__(256) void build_g_kernel(
    const float* __restrict__ emb, const int* __restrict__ spans,
    const float* __restrict__ attns, float* __restrict__ g)
{
    int blk = blockIdx.x;           // 256 = b*128 + s
    int b = blk >> 7;
    int t0 = spans[blk];
    int e = threadIdx.x;            // 256 = E
    const float* eb = emb + ((size_t)(b * 2048 + t0)) * 256 + e;
    const float* at = attns + b * 2048 + t0;
    float start = eb[0];
    float endv  = eb[7 * 256];
    float wsum = 0.f;
#pragma unroll
    for (int w = 0; w < 8; ++w) wsum = fmaf(eb[w * 256], at[w], wsum);
    g[(size_t)blk * 768 + e]       = start;
    g[(size_t)blk * 768 + 256 + e] = endv;
    g[(size_t)blk * 768 + 512 + e] = wsum;
}

// ---------------- fused u/v/ment per g-row ----------------
__global__ __launch_bounds__(256) void uvm_kernel(
    const float* __restrict__ g,
    const float* __restrict__ pw1, const float* __restrict__ pb1,
    const float* __restrict__ mw1, const float* __restrict__ mb1,
    const float* __restrict__ mw2, const float* __restrict__ mb2,
    const float* __restrict__ mw3, const float* __restrict__ mb3,
    float* __restrict__ u_pad, float* __restrict__ v_pad, float* __restrict__ ment)
{
    int row = blockIdx.x;   // 256
    int t = threadIdx.x;
    __shared__ float xs[768];
    __shared__ float hs[150];
    __shared__ float red[4];
    for (int idx = t; idx < 768; idx += 256) xs[idx] = g[(size_t)row * 768 + idx];
    __syncthreads();

    float au = 0.f, av = 0.f, am = 0.f;
    if (t < 150) {
        au = pb1[t];
        am = mb1[t];
        for (int e = 0; e < 768; ++e) {
            float ge = xs[e];
            au = fmaf(ge, pw1[e * 150 + t], au);
            av = fmaf(ge, pw1[(768 + e) * 150 + t], av);
            am = fmaf(ge, mw1[e * 150 + t], am);
        }
    }
    if (t < 192) {
        u_pad[row * 192 + t] = (t < 150) ? au : 0.f;
        v_pad[row * 192 + t] = (t < 150) ? av : 0.f;
    }
    if (t < 150) hs[t] = fmaxf(am, 0.f);
    __syncthreads();
    float c = 0.f;
    if (t < 150) {
        c = mb2[t];
        for (int k = 0; k < 150; ++k) c = fmaf(hs[k], mw2[k * 150 + t], c);
    }
    float h2v = fmaxf(c, 0.f);
    float part = (t < 150) ? h2v * mw3[t] : 0.f;
#pragma unroll
    for (int off = 32; off; off >>= 1) part += __shfl_xor(part, off);
    if ((t & 63) == 0) red[t >> 6] = part;
    __syncthreads();
    if (t == 0) ment[row] = red[0] + red[1] + red[2] + red[3] + mb3[0];
}

// ---------------- the heavy pair kernel ----------------
// block = (b, i); 8 waves; wave w owns j in [16w, 16w+16)
__global__ __launch_bounds__(512) void pair_kernel(
    const float* __restrict__ g,
    const float* __restrict__ u_pad, const float* __restrict__ v_pad,
    const float* __restrict__ w1c_pad, const float* __restrict__ w2_pad,
    const float* __restrict__ b2_pad, const float* __restrict__ w3_pad,
    const float* __restrict__ pb3, const float* __restrict__ ment,
    float* __restrict__ out)
{
    const int blk = blockIdx.x;          // 256
    const int b = blk >> 7, i = blk & 127;
    const int lane = threadIdx.x & 63;
    const int wid  = threadIdx.x >> 6;   // 8 waves
    const int row_i = b * 128 + i;
    const int jbase = wid * 16;

    __shared__ float gi_s[768];
    __shared__ float p_s[8][64][20];     // per-wave staging of gi*gj, transposed+padded

    for (int idx = threadIdx.x; idx < 768; idx += 512)
        gi_s[idx] = g[(size_t)row_i * 768 + idx];
    __syncthreads();

    float a0[16], a1[16], a2[16];
#pragma unroll
    for (int jj = 0; jj < 16; ++jj) { a0[jj] = 0.f; a1[jj] = 0.f; a2[jj] = 0.f; }

    for (int e0 = 0; e0 < 768; e0 += 64) {
        // stage p[e][jj] = gi[e] * gj[jj][e] for e = e0 + lane
        float gie = gi_s[e0 + lane];
        float pj[16];
#pragma unroll
        for (int jj = 0; jj < 16; ++jj)
            pj[jj] = gie * g[(size_t)(b * 128 + jbase + jj) * 768 + e0 + lane];
        __syncthreads();   // prior chunk's reads complete before overwrite
#pragma unroll
        for (int q = 0; q < 4; ++q) {
            float4 v4 = make_float4(pj[4 * q], pj[4 * q + 1], pj[4 * q + 2], pj[4 * q + 3]);
            *reinterpret_cast<float4*>(&p_s[wid][lane][4 * q]) = v4;
        }
        __syncthreads();

        for (int el = 0; el < 64; ++el) {
            const float* wrow = w1c_pad + (size_t)(e0 + el) * 192;
            float w_0 = wrow[lane];
            float w_1 = wrow[64 + lane];
            float w_2 = wrow[128 + lane];       // zero for lane>=22
            float pv[16];
            const float4* pr = reinterpret_cast<const float4*>(&p_s[wid][el][0]);
            *reinterpret_cast<float4*>(&pv[0])  = pr[0];
            *reinterpret_cast<float4*>(&pv[4])  = pr[1];
            *reinterpret_cast<float4*>(&pv[8])  = pr[2];
            *reinterpret_cast<float4*>(&pv[12]) = pr[3];
#pragma unroll
            for (int jj = 0; jj < 16; ++jj) {
                a0[jj] = fmaf(pv[jj], w_0, a0[jj]);
                a1[jj] = fmaf(pv[jj], w_1, a1[jj]);
                a2[jj] = fmaf(pv[jj], w_2, a2[jj]);
            }
        }
    }

    // epilogue layer 1: + u_i + v_j, relu  (pads are zero beyond h=149)
    float u0 = u_pad[row_i * 192 + lane];
    float u1 = u_pad[row_i * 192 + 64 + lane];
    float u2 = u_pad[row_i * 192 + 128 + lane];
#pragma unroll
    for (int jj = 0; jj < 16; ++jj) {
        int rj = b * 128 + jbase + jj;
        a0[jj] = fmaxf(a0[jj] + u0 + v_pad[rj * 192 + lane], 0.f);
        a1[jj] = fmaxf(a1[jj] + u1 + v_pad[rj * 192 + 64 + lane], 0.f);
        a2[jj] = fmaxf(a2[jj] + u2 + v_pad[rj * 192 + 128 + lane], 0.f);
    }

    // layer 2: h2 = relu(h1 @ w2 + b2), h1 broadcast via shfl
    float c0[16], c1[16], c2[16];
    float cb0 = b2_pad[lane], cb1 = b2_pad[64 + lane], cb2 = b2_pad[128 + lane];
#pragma unroll
    for (int jj = 0; jj < 16; ++jj) { c0[jj] = cb0; c1[jj] = cb1; c2[jj] = cb2; }

    for (int kk = 0; kk < 64; ++kk) {
        const float* w2r = w2_pad + kk * 192;
        float w_0 = w2r[lane], w_1 = w2r[64 + lane], w_2 = w2r[128 + lane];
#pragma unroll
        for (int jj = 0; jj < 16; ++jj) {
            float hv = __shfl(a0[jj], kk);
            c0[jj] = fmaf(hv, w_0, c0[jj]);
            c1[jj] = fmaf(hv, w_1, c1[jj]);
            c2[jj] = fmaf(hv, w_2, c2[jj]);
        }
    }
    for (int kk = 0; kk < 64; ++kk) {
        const float* w2r = w2_pad + (64 + kk) * 192;
        float w_0 = w2r[lane], w_1 = w2r[64 + lane], w_2 = w2r[128 + lane];
#pragma unroll
        for (int jj = 0; jj < 16; ++jj) {
            float hv = __shfl(a1[jj], kk);
            c0[jj] = fmaf(hv, w_0, c0[jj]);
            c1[jj] = fmaf(hv, w_1, c1[jj]);
            c2[jj] = fmaf(hv, w_2, c2[jj]);
        }
    }
    for (int kk = 0; kk < 22; ++kk) {
        const float* w2r = w2_pad + (128 + kk) * 192;
        float w_0 = w2r[lane], w_1 = w2r[64 + lane], w_2 = w2r[128 + lane];
#pragma unroll
        for (int jj = 0; jj < 16; ++jj) {
            float hv = __shfl(a2[jj], kk);
            c0[jj] = fmaf(hv, w_0, c0[jj]);
            c1[jj] = fmaf(hv, w_1, c1[jj]);
            c2[jj] = fmaf(hv, w_2, c2[jj]);
        }
    }

    // layer 3 + combine with mention scores
    float w30 = w3_pad[lane], w31 = w3_pad[64 + lane], w32 = w3_pad[128 + lane];
    float b3v = pb3[0];
    float mi  = ment[row_i];
    float myout = 0.f;
#pragma unroll
    for (int jj = 0; jj < 16; ++jj) {
        float d0 = fmaxf(c0[jj], 0.f);
        float d1 = fmaxf(c1[jj], 0.f);
        float d2 = fmaxf(c2[jj], 0.f);
        float part = d0 * w30 + d1 * w31 + d2 * w32;
#pragma unroll
        for (int off = 32; off; off >>= 1) part += __shfl_xor(part, off);
        float mj = ment[b * 128 + jbase + jj];
        float val = (part + b3v + mi + mj) * (1.0f / 3.0f);
        if (lane == jj) myout = val;
    }
    if (lane < 16)
        out[(size_t)b * 16384 + (size_t)i * 128 + jbase + lane] = myout;
}

extern "C" void kernel_launch(void* const* d_in, const int* in_sizes, int n_in,
                              void* d_out, int out_size, void* d_ws, size_t ws_size,
                              hipStream_t stream)
{
    const float* emb   = (const float*)d_in[0];
    const int*   spans = (const int*)d_in[1];
    const float* aw1 = (const float*)d_in[2];
    const float* ab1 = (const float*)d_in[3];
    const float* aw2 = (const float*)d_in[4];
    const float* ab2 = (const float*)d_in[5];
    const float* aw3 = (const float*)d_in[6];
    const float* ab3 = (const float*)d_in[7];
    const float* mw1 = (const float*)d_in[8];
    const float* mb1 = (const float*)d_in[9];
    const float* mw2 = (const float*)d_in[10];
    const float* mb2 = (const float*)d_in[11];
    const float* mw3 = (const float*)d_in[12];
    const float* mb3 = (const float*)d_in[13];
    const float* pw1 = (const float*)d_in[14];
    const float* pb1 = (const float*)d_in[15];
    const float* pw2 = (const float*)d_in[16];
    const float* pb2 = (const float*)d_in[17];
    const float* pw3 = (const float*)d_in[18];
    const float* pb3 = (const float*)d_in[19];

    float* ws      = (float*)d_ws;
    float* attns   = ws;            // 4096
    float* g       = ws + 4096;     // 196608
    float* ment    = ws + 200704;   // 256
    float* u_pad   = ws + 200960;   // 49152
    float* v_pad   = ws + 250112;   // 49152
    float* w1c_pad = ws + 299264;   // 147456
    float* w2_pad  = ws + 446720;   // 28800
    float* b2_pad  = ws + 475520;   // 192
    float* w3_pad  = ws + 475712;   // 192

    prep_pads_kernel<<<690, 256, 0, stream>>>(pw1, pw2, pb2, pw3,
                                              w1c_pad, w2_pad, b2_pad, w3_pad);
    mlp_scalar_kernel<256, 4><<<256, 256, 0, stream>>>(emb, aw1, ab1, aw2, ab2, aw3, ab3, attns);
    build_g_kernel<<<256, 256, 0, stream>>>(emb, spans, attns, g);
    uvm_kernel<<<256, 256, 0, stream>>>(g, pw1, pb1, mw1, mb1, mw2, mb2, mw3, mb3,
                                        u_pad, v_pad, ment);
    pair_kernel<<<256, 512, 0, stream>>>(g, u_pad, v_pad, w1c_pad, w2_pad, b2_pad,
                                         w3_pad, pb3, ment, (float*)d_out);
}

// Round 2
// 111.194 us; speedup vs baseline: 2.5338x; 2.5338x over previous
//
#include <hip/hip_runtime.h>
#include <hip/hip_bf16.h>

// Problem: B=2, T=2048, E=256, S=128, W=8, H=150
// pairs@w1 = gi@w1a + gj@w1b + (gi*gj)@w1c
//   u_i = gi@w1a + b1   (256 rows, f32, uvm_kernel)
//   v_j = gj@w1b        (256 rows, f32, uvm_kernel)
//   cross_i = (G_b scaled col-wise by gi) @ W1c   -> per-(b,i) MFMA GEMM 128x768x192
// Layers 1+2 of the pair MLP run on matrix cores (bf16 in, f32 acc);
// layer 3 + mention combine on VALU.
//
// ws layout (float units):
//   attns   [4096]          @ 0
//   g       [256*768]       @ 4096
//   ment    [256]           @ 200704
//   u_pad   [256*192]       @ 200960   (includes pair_b1; zero-padded h>=150)
//   v_pad   [256*192]       @ 250112
//   b2_pad  [192]           @ 299264
//   w3_pad  [192]           @ 299456
//   w1cT    [192][768] bf16 @ 299648   (73728 float slots)
//   w2T     [192][160] bf16 @ 373376   (15360 float slots)
// end @ 388736 floats = 1.55 MB

typedef __bf16 bf16;
typedef __attribute__((ext_vector_type(8))) short v8s;   // 8 bf16 bits (4 VGPRs)
typedef __attribute__((ext_vector_type(8))) __bf16 v8bf;
typedef __attribute__((ext_vector_type(4))) float v4f;

#define MFMA_BF16(A, B, C) __builtin_amdgcn_mfma_f32_16x16x32_bf16((A), (B), (C), 0, 0, 0)

// ---------------- prep: transposed, zero-padded bf16 copies of pair weights ----------------
__global__ __launch_bounds__(256) void prep_kernel(
    const float* __restrict__ pw1, const float* __restrict__ pw2,
    const float* __restrict__ pb2, const float* __restrict__ pw3,
    bf16* __restrict__ w1cT, bf16* __restrict__ w2T,
    float* __restrict__ b2_pad, float* __restrict__ w3_pad)
{
    int idx = blockIdx.x * 256 + threadIdx.x;
    if (idx < 147456) {                    // w1cT[h][e] = W1c[e][h], [192][768]
        int h = idx / 768, e = idx % 768;
        float v = (h < 150) ? pw1[(1536 + e) * 150 + h] : 0.f;
        w1cT[idx] = (bf16)v;
    } else if (idx < 178176) {             // w2T[n][k] = W2[k][n], [192][160]
        int j = idx - 147456;
        int n = j / 160, k = j % 160;
        float v = (n < 150 && k < 150) ? pw2[k * 150 + n] : 0.f;
        w2T[j] = (bf16)v;
    } else if (idx < 178368) {
        int h = idx - 178176;
        b2_pad[h] = (h < 150) ? pb2[h] : 0.f;
    } else if (idx < 178560) {
        int h = idx - 178368;
        w3_pad[h] = (h < 150) ? pw3[h] : 0.f;
    }
}

// ---------------- generic scalar-output MLP (d_in -> 150 -> 150 -> 1) ----------------
template <int DIN, int RPW>
__global__ __launch_bounds__(256) void mlp_scalar_kernel(
    const float* __restrict__ x,
    const float* __restrict__ w1, const float* __restrict__ b1,
    const float* __restrict__ w2, const float* __restrict__ b2,
    const float* __restrict__ w3, const float* __restrict__ b3,
    float* __restrict__ out)
{
    __shared__ float xs[4][RPW][DIN];
    const int lane = threadIdx.x & 63;
    const int wid  = threadIdx.x >> 6;
    const int rbase = blockIdx.x * (4 * RPW) + wid * RPW;

    for (int idx = lane; idx < RPW * DIN; idx += 64) {
        int r = idx / DIN, e = idx % DIN;
        xs[wid][r][e] = x[(size_t)(rbase + r) * DIN + e];
    }
    __syncthreads();

    const bool l22 = lane < 22;
    const int  h2i = l22 ? (128 + lane) : 0;

    float a0[RPW], a1[RPW], a2[RPW];
#pragma unroll
    for (int r = 0; r < RPW; ++r) { a0[r] = 0.f; a1[r] = 0.f; a2[r] = 0.f; }

    for (int e = 0; e < DIN; ++e) {
        float w_0 = w1[e * 150 + lane];
        float w_1 = w1[e * 150 + 64 + lane];
        float w_2 = w1[e * 150 + h2i];
#pragma unroll
        for (int r = 0; r < RPW; ++r) {
            float xv = xs[wid][r][e];
            a0[r] = fmaf(xv, w_0, a0[r]);
            a1[r] = fmaf(xv, w_1, a1[r]);
            a2[r] = fmaf(xv, w_2, a2[r]);
        }
    }
    float bb0 = b1[lane], bb1 = b1[64 + lane], bb2 = b1[h2i];
#pragma unroll
    for (int r = 0; r < RPW; ++r) {
        a0[r] = fmaxf(a0[r] + bb0, 0.f);
        a1[r] = fmaxf(a1[r] + bb1, 0.f);
        a2[r] = fmaxf(a2[r] + bb2, 0.f);
    }

    float c0[RPW], c1[RPW], c2[RPW];
    float cb0 = b2[lane], cb1 = b2[64 + lane], cb2 = b2[h2i];
#pragma unroll
    for (int r = 0; r < RPW; ++r) { c0[r] = cb0; c1[r] = cb1; c2[r] = cb2; }

    for (int kk = 0; kk < 64; ++kk) {
        float w_0 = w2[kk * 150 + lane];
        float w_1 = w2[kk * 150 + 64 + lane];
        float w_2 = w2[kk * 150 + h2i];
#pragma unroll
        for (int r = 0; r < RPW; ++r) {
            float hv = __shfl(a0[r], kk);
            c0[r] = fmaf(hv, w_0, c0[r]);
            c1[r] = fmaf(hv, w_1, c1[r]);
            c2[r] = fmaf(hv, w_2, c2[r]);
        }
    }
    for (int kk = 0; kk < 64; ++kk) {
        int k = 64 + kk;
        float w_0 = w2[k * 150 + lane];
        float w_1 = w2[k * 150 + 64 + lane];
        float w_2 = w2[k * 150 + h2i];
#pragma unroll
        for (int r = 0; r < RPW; ++r) {
            float hv = __shfl(a1[r], kk);
            c0[r] = fmaf(hv, w_0, c0[r]);
            c1[r] = fmaf(hv, w_1, c1[r]);
            c2[r] = fmaf(hv, w_2, c2[r]);
        }
    }
    for (int kk = 0; kk < 22; ++kk) {
        int k = 128 + kk;
        float w_0 = w2[k * 150 + lane];
        float w_1 = w2[k * 150 + 64 + lane];
        float w_2 = w2[k * 150 + h2i];
#pragma unroll
        for (int r = 0; r < RPW; ++r) {
            float hv = __shfl(a2[r], kk);
            c0[r] = fmaf(hv, w_0, c0[r]);
            c1[r] = fmaf(hv, w_1, c1[r]);
            c2[r] = fmaf(hv, w_2, c2[r]);
        }
    }

    float w30 = w3[lane], w31 = w3[64 + lane], w32 = w3[h2i];
    float b3v = b3[0];
#pragma unroll
    for (int r = 0; r < RPW; ++r) {
        float d0 = fmaxf(c0[r], 0.f);
        float d1 = fmaxf(c1[r], 0.f);
        float d2 = fmaxf(c2[r], 0.f);
        float part = d0 * w30 + d1 * w31 + (l22 ? d2 * w32 : 0.f);
#pragma unroll
        for (int off = 32; off; off >>= 1) part += __shfl_xor(part, off);
        if (lane == 0) out[rbase + r] = part + b3v;
    }
}

// ---------------- build g = [start, end, weighted] ----------------
__global__ __launch_bounds__(256) void build_g_kernel(
    const float* __restrict__ emb, const int* __restrict__ spans,
    const float* __restrict__ attns, float* __restrict__ g)
{
    int blk = blockIdx.x;
    int b = blk >> 7;
    int t0 = spans[blk];
    int e = threadIdx.x;
    const float* eb = emb + ((size_t)(b * 2048 + t0)) * 256 + e;
    const float* at = attns + b * 2048 + t0;
    float start = eb[0];
    float endv  = eb[7 * 256];
    float wsum = 0.f;
#pragma unroll
    for (int w = 0; w < 8; ++w) wsum = fmaf(eb[w * 256], at[w], wsum);
    g[(size_t)blk * 768 + e]       = start;
    g[(size_t)blk * 768 + 256 + e] = endv;
    g[(size_t)blk * 768 + 512 + e] = wsum;
}

// ---------------- fused u/v/ment per g-row ----------------
__global__ __launch_bounds__(256) void uvm_kernel(
    const float* __restrict__ g,
    const float* __restrict__ pw1, const float* __restrict__ pb1,
    const float* __restrict__ mw1, const float* __restrict__ mb1,
    const float* __restrict__ mw2, const float* __restrict__ mb2,
    const float* __restrict__ mw3, const float* __restrict__ mb3,
    float* __restrict__ u_pad, float* __restrict__ v_pad, float* __restrict__ ment)
{
    int row = blockIdx.x;
    int t = threadIdx.x;
    __shared__ float xs[768];
    __shared__ float hs[150];
    __shared__ float red[4];
    for (int idx = t; idx < 768; idx += 256) xs[idx] = g[(size_t)row * 768 + idx];
    __syncthreads();

    float au = 0.f, av = 0.f, am = 0.f;
    if (t < 150) {
        au = pb1[t];
        am = mb1[t];
        for (int e = 0; e < 768; ++e) {
            float ge = xs[e];
            au = fmaf(ge, pw1[e * 150 + t], au);
            av = fmaf(ge, pw1[(768 + e) * 150 + t], av);
            am = fmaf(ge, mw1[e * 150 + t], am);
        }
    }
    if (t < 192) {
        u_pad[row * 192 + t] = (t < 150) ? au : 0.f;
        v_pad[row * 192 + t] = (t < 150) ? av : 0.f;
    }
    if (t < 150) hs[t] = fmaxf(am, 0.f);
    __syncthreads();
    float c = 0.f;
    if (t < 150) {
        c = mb2[t];
        for (int k = 0; k < 150; ++k) c = fmaf(hs[k], mw2[k * 150 + t], c);
    }
    float h2v = fmaxf(c, 0.f);
    float part = (t < 150) ? h2v * mw3[t] : 0.f;
#pragma unroll
    for (int off = 32; off; off >>= 1) part += __shfl_xor(part, off);
    if ((t & 63) == 0) red[t >> 6] = part;
    __syncthreads();
    if (t == 0) ment[row] = red[0] + red[1] + red[2] + red[3] + mb3[0];
}

// ---------------- MFMA pair kernel ----------------
// block = (b,i), 512 threads = 8 waves arranged 2(M) x 4(N).
// Layer1: [128 x 768] @ [768 x 192] ; Layer2: [128 x 160] @ [160 x 192].
__device__ __forceinline__ v8bf mul_cvt8(float4 xa, float4 xb, float4 sa, float4 sb) {
    v8bf w;
    w[0] = (bf16)(xa.x * sa.x); w[1] = (bf16)(xa.y * sa.y);
    w[2] = (bf16)(xa.z * sa.z); w[3] = (bf16)(xa.w * sa.w);
    w[4] = (bf16)(xb.x * sb.x); w[5] = (bf16)(xb.y * sb.y);
    w[6] = (bf16)(xb.z * sb.z); w[7] = (bf16)(xb.w * sb.w);
    return w;
}

__global__ __launch_bounds__(512) void pair_mfma_kernel(
    const float* __restrict__ g,
    const float* __restrict__ u_pad, const float* __restrict__ v_pad,
    const bf16* __restrict__ w1cT, const bf16* __restrict__ w2T,
    const float* __restrict__ b2_pad, const float* __restrict__ w3_pad,
    const float* __restrict__ pb3, const float* __restrict__ ment,
    float* __restrict__ out)
{
    // LDS plan (bytes):
    //  layer1: a_lds [2][128][72]bf16 @0 (36864) | b_lds [2][192][72]bf16 @36864 (55296) | gi_s[768]f32 @92160 (3072)
    //  layer2: h1_lds [128][168]bf16 @0 (43008)  | w2_lds [192][168]bf16 @43008 (64512)
    //  layer3: red [128][4]f32 @107520 (2048)   -> total 109568
    __shared__ __attribute__((aligned(16))) char smem[109568];
    bf16*  a_lds  = (bf16*)smem;
    bf16*  b_lds  = (bf16*)(smem + 36864);
    float* gi_s   = (float*)(smem + 92160);
    bf16*  h1_lds = (bf16*)smem;
    bf16*  w2_lds = (bf16*)(smem + 43008);
    float* red    = (float*)(smem + 107520);

    const int blk   = blockIdx.x;      // b*128 + i
    const int b     = blk >> 7;
    const int row_i = blk;
    const int tid   = threadIdx.x;
    const int lane  = tid & 63;
    const int wm    = (tid >> 6) >> 2; // 0..1 -> M offset wm*64
    const int wn    = (tid >> 6) & 3;  // 0..3 -> N offset wn*48
    const int l15   = lane & 15;
    const int lk    = (lane >> 4) * 8; // k sub-offset for frags

    // staging roles
    const int aj = tid >> 2;           // 0..127  (A row)
    const int ae = (tid & 3) * 16;     // 0/16/32/48 (A k-chunk)
    const int bn = tid >> 1;           // B row (valid while tid<384)
    const int bk = (tid & 1) * 32;     // B k-chunk

    // gi into LDS
    if (tid < 192)
        *(float4*)&gi_s[tid * 4] = *(const float4*)&g[(size_t)row_i * 768 + tid * 4];
    __syncthreads();

    // ---- prologue: stage chunk 0 ----
    {
        const float* gs = g + (size_t)(b * 128 + aj) * 768 + ae;
        float4 x0 = *(const float4*)(gs + 0),  x1 = *(const float4*)(gs + 4);
        float4 x2 = *(const float4*)(gs + 8),  x3 = *(const float4*)(gs + 12);
        const float* gp = gi_s + ae;
        float4 s0 = *(const float4*)(gp + 0),  s1 = *(const float4*)(gp + 4);
        float4 s2 = *(const float4*)(gp + 8),  s3 = *(const float4*)(gp + 12);
        bf16* ad = a_lds + aj * 72 + ae;
        *(v8bf*)ad       = mul_cvt8(x0, x1, s0, s1);
        *(v8bf*)(ad + 8) = mul_cvt8(x2, x3, s2, s3);
        if (tid < 384) {
            const bf16* bs = w1cT + bn * 768 + bk;
            bf16* bd = b_lds + bn * 72 + bk;
#pragma unroll
            for (int c2 = 0; c2 < 4; ++c2)
                *(uint4*)(bd + c2 * 8) = *(const uint4*)(bs + c2 * 8);
        }
    }
    __syncthreads();

    v4f acc[4][3];
#pragma unroll
    for (int mf = 0; mf < 4; ++mf)
#pragma unroll
        for (int nf = 0; nf < 3; ++nf) acc[mf][nf] = (v4f){0.f, 0.f, 0.f, 0.f};

    // ---- main K loop: 12 chunks of 64 ----
    int cur = 0;
    for (int c = 0; c < 12; ++c) {
        float4 x0, x1, x2, x3;
        uint4 bv0, bv1, bv2, bv3;
        if (c < 11) {   // T14: issue next-chunk global loads before MFMA phase
            const int e0 = (c + 1) * 64;
            const float* gs = g + (size_t)(b * 128 + aj) * 768 + e0 + ae;
            x0 = *(const float4*)(gs + 0);  x1 = *(const float4*)(gs + 4);
            x2 = *(const float4*)(gs + 8);  x3 = *(const float4*)(gs + 12);
            if (tid < 384) {
                const bf16* bs = w1cT + bn * 768 + e0 + bk;
                bv0 = *(const uint4*)(bs + 0);  bv1 = *(const uint4*)(bs + 8);
                bv2 = *(const uint4*)(bs + 16); bv3 = *(const uint4*)(bs + 24);
            }
        }

        const bf16* ab = a_lds + cur * 9216;
        const bf16* bb = b_lds + cur * 13824;
#pragma unroll
        for (int ks = 0; ks < 2; ++ks) {
            const int kb = ks * 32 + lk;
            v8s af[4], bfr[3];
#pragma unroll
            for (int mf = 0; mf < 4; ++mf)
                af[mf] = *(const v8s*)&ab[(wm * 64 + mf * 16 + l15) * 72 + kb];
#pragma unroll
            for (int nf = 0; nf < 3; ++nf)
                bfr[nf] = *(const v8s*)&bb[(wn * 48 + nf * 16 + l15) * 72 + kb];
#pragma unroll
            for (int mf = 0; mf < 4; ++mf)
#pragma unroll
                for (int nf = 0; nf < 3; ++nf)
                    acc[mf][nf] = MFMA_BF16(af[mf], bfr[nf], acc[mf][nf]);
        }

        if (c < 11) {   // write next chunk into other buffer
            const float* gp = gi_s + (c + 1) * 64 + ae;
            float4 s0 = *(const float4*)(gp + 0),  s1 = *(const float4*)(gp + 4);
            float4 s2 = *(const float4*)(gp + 8),  s3 = *(const float4*)(gp + 12);
            bf16* ad = a_lds + (cur ^ 1) * 9216 + aj * 72 + ae;
            *(v8bf*)ad       = mul_cvt8(x0, x1, s0, s1);
            *(v8bf*)(ad + 8) = mul_cvt8(x2, x3, s2, s3);
            if (tid < 384) {
                bf16* bd = b_lds + (cur ^ 1) * 13824 + bn * 72 + bk;
                *(uint4*)(bd + 0)  = bv0; *(uint4*)(bd + 8)  = bv1;
                *(uint4*)(bd + 16) = bv2; *(uint4*)(bd + 24) = bv3;
            }
        }
        __syncthreads();
        cur ^= 1;
    }

    // ---- stage W2^T into LDS (region free after final barrier above) ----
    if (tid < 384) {
        const int n = tid >> 1, kh = (tid & 1) * 80;
        const bf16* src = w2T + n * 160 + kh;
        bf16* dst = w2_lds + n * 168 + kh;
#pragma unroll
        for (int c2 = 0; c2 < 10; ++c2)
            *(uint4*)(dst + c2 * 8) = *(const uint4*)(src + c2 * 8);
    }

    // ---- layer1 epilogue: h1 = relu(cross + u_i + v_j) -> LDS bf16 ----
    {
        const float uh0 = u_pad[row_i * 192 + wn * 48 + 0  + l15];
        const float uh1 = u_pad[row_i * 192 + wn * 48 + 16 + l15];
        const float uh2 = u_pad[row_i * 192 + wn * 48 + 32 + l15];
#pragma unroll
        for (int mf = 0; mf < 4; ++mf) {
#pragma unroll
            for (int r = 0; r < 4; ++r) {
                const int j = wm * 64 + mf * 16 + (lane >> 4) * 4 + r;
                const float* vrow = v_pad + (size_t)(b * 128 + j) * 192 + wn * 48 + l15;
                const float v0 = acc[mf][0][r] + uh0 + vrow[0];
                const float v1 = acc[mf][1][r] + uh1 + vrow[16];
                const float v2 = acc[mf][2][r] + uh2 + vrow[32];
                bf16* hrow = h1_lds + j * 168 + wn * 48 + l15;
                hrow[0] = (bf16)fmaxf(v0, 0.f);          // cols < 160 always
                if (wn < 3) {                            // skip cols >= 160 (zero/unused)
                    hrow[16] = (bf16)fmaxf(v1, 0.f);
                    hrow[32] = (bf16)fmaxf(v2, 0.f);
                }
            }
        }
    }
    __syncthreads();

    // ---- layer 2: h2 = h1 @ W2 (K=160), bias+relu folded into layer 3 ----
    v4f acc2[4][3];
#pragma unroll
    for (int mf = 0; mf < 4; ++mf)
#pragma unroll
        for (int nf = 0; nf < 3; ++nf) acc2[mf][nf] = (v4f){0.f, 0.f, 0.f, 0.f};

#pragma unroll
    for (int ks = 0; ks < 5; ++ks) {
        const int kb = ks * 32 + lk;
        v8s af[4], bfr[3];
#pragma unroll
        for (int mf = 0; mf < 4; ++mf)
            af[mf] = *(const v8s*)&h1_lds[(wm * 64 + mf * 16 + l15) * 168 + kb];
#pragma unroll
        for (int nf = 0; nf < 3; ++nf)
            bfr[nf] = *(const v8s*)&w2_lds[(wn * 48 + nf * 16 + l15) * 168 + kb];
#pragma unroll
        for (int mf = 0; mf < 4; ++mf)
#pragma unroll
            for (int nf = 0; nf < 3; ++nf)
                acc2[mf][nf] = MFMA_BF16(af[mf], bfr[nf], acc2[mf][nf]);
    }

    // ---- layer 3 + combine ----
    const float b2v0 = b2_pad[wn * 48 + 0  + l15], w3v0 = w3_pad[wn * 48 + 0  + l15];
    const float b2v1 = b2_pad[wn * 48 + 16 + l15], w3v1 = w3_pad[wn * 48 + 16 + l15];
    const float b2v2 = b2_pad[wn * 48 + 32 + l15], w3v2 = w3_pad[wn * 48 + 32 + l15];
#pragma unroll
    for (int mf = 0; mf < 4; ++mf) {
#pragma unroll
        for (int r = 0; r < 4; ++r) {
            float p = fmaxf(acc2[mf][0][r] + b2v0, 0.f) * w3v0
                    + fmaxf(acc2[mf][1][r] + b2v1, 0.f) * w3v1
                    + fmaxf(acc2[mf][2][r] + b2v2, 0.f) * w3v2;
            p += __shfl_xor(p, 1);
            p += __shfl_xor(p, 2);
            p += __shfl_xor(p, 4);
            p += __shfl_xor(p, 8);
            if (l15 == 0) {
                const int j = wm * 64 + mf * 16 + (lane >> 4) * 4 + r;
                red[j * 4 + wn] = p;
            }
        }
    }
    __syncthreads();
    if (tid < 128) {
        const float s = red[tid * 4 + 0] + red[tid * 4 + 1] + red[tid * 4 + 2] + red[tid * 4 + 3];
        out[(size_t)blk * 128 + tid] =
            (s + pb3[0] + ment[row_i] + ment[b * 128 + tid]) * (1.f / 3.f);
    }
}

extern "C" void kernel_launch(void* const* d_in, const int* in_sizes, int n_in,
                              void* d_out, int out_size, void* d_ws, size_t ws_size,
                              hipStream_t stream)
{
    const float* emb   = (const float*)d_in[0];
    const int*   spans = (const int*)d_in[1];
    const float* aw1 = (const float*)d_in[2];
    const float* ab1 = (const float*)d_in[3];
    const float* aw2 = (const float*)d_in[4];
    const float* ab2 = (const float*)d_in[5];
    const float* aw3 = (const float*)d_in[6];
    const float* ab3 = (const float*)d_in[7];
    const float* mw1 = (const float*)d_in[8];
    const float* mb1 = (const float*)d_in[9];
    const float* mw2 = (const float*)d_in[10];
    const float* mb2 = (const float*)d_in[11];
    const float* mw3 = (const float*)d_in[12];
    const float* mb3 = (const float*)d_in[13];
    const float* pw1 = (const float*)d_in[14];
    const float* pb1 = (const float*)d_in[15];
    const float* pw2 = (const float*)d_in[16];
    const float* pb2 = (const float*)d_in[17];
    const float* pw3 = (const float*)d_in[18];
    const float* pb3 = (const float*)d_in[19];

    float* ws     = (float*)d_ws;
    float* attns  = ws;             // 4096
    float* g      = ws + 4096;      // 196608
    float* ment   = ws + 200704;    // 256
    float* u_pad  = ws + 200960;    // 49152
    float* v_pad  = ws + 250112;    // 49152
    float* b2_pad = ws + 299264;    // 192
    float* w3_pad = ws + 299456;    // 192
    bf16*  w1cT   = (bf16*)(ws + 299648);   // 192*768 bf16
    bf16*  w2T    = (bf16*)(ws + 373376);   // 192*160 bf16

    prep_kernel<<<698, 256, 0, stream>>>(pw1, pw2, pb2, pw3, w1cT, w2T, b2_pad, w3_pad);
    mlp_scalar_kernel<256, 4><<<256, 256, 0, stream>>>(emb, aw1, ab1, aw2, ab2, aw3, ab3, attns);
    build_g_kernel<<<256, 256, 0, stream>>>(emb, spans, attns, g);
    uvm_kernel<<<256, 256, 0, stream>>>(g, pw1, pb1, mw1, mb1, mw2, mb2, mw3, mb3,
                                        u_pad, v_pad, ment);
    pair_mfma_kernel<<<256, 512, 0, stream>>>(g, u_pad, v_pad, w1cT, w2T,
                                              b2_pad, w3_pad, pb3, ment, (float*)d_out);
}

// Round 3
// 81.407 us; speedup vs baseline: 3.4609x; 1.3659x over previous
//
#include <hip/hip_runtime.h>
#include <hip/hip_bf16.h>

// Problem: B=2, T=2048, E=256, S=128, W=8, H=150
// All three MLPs run on matrix cores (bf16 in, f32 acc):
//   attn:  emb[4096x256] @ W1a -> H -> H -> 1           (32 blocks, M=128)
//   uvm:   g[256x768] @ {pw1a | pw1b | mw1}             (6 blocks: 2 row-tiles x 3 sections)
//   pair:  cross_i = (G_b scaled by gi) @ W1c, + layer2 (256 blocks, as round 2)
// pairs@w1 = gi@w1a + gj@w1b + (gi*gj)@w1c
//
// ws layout (float units):
//   attns   [4096]            @ 0
//   g       [196608]          @ 4096
//   ment    [256]             @ 200704
//   u_pad   [49152]           @ 200960
//   v_pad   [49152]           @ 250112
//   bias    [1728 = 9*192]    @ 299264  (pb1,pb2,pw3,ab1,ab2,aw3,mb1,mb2,mw3 padded)
//   w1cT    bf16[192][768]    @ 300992  (73728 f)
//   w2pT    bf16[192][160]    @ 374720  (15360 f)
//   w1aT    bf16[192][256]    @ 390080  (24576 f)
//   w2aT    bf16[192][160]    @ 414656  (15360 f)
//   w2mT    bf16[192][160]    @ 430016  (15360 f)
//   wuvmT   bf16[3][192][768] @ 445376  (221184 f)
// end @ 666560 floats = 2.67 MB

typedef __bf16 bf16;
typedef __attribute__((ext_vector_type(8))) short v8s;
typedef __attribute__((ext_vector_type(8))) __bf16 v8bf;
typedef __attribute__((ext_vector_type(4))) float v4f;

#define MFMA_BF16(A, B, C) __builtin_amdgcn_mfma_f32_16x16x32_bf16((A), (B), (C), 0, 0, 0)

__device__ __forceinline__ v8bf mul_cvt8(float4 xa, float4 xb, float4 sa, float4 sb) {
    v8bf w;
    w[0] = (bf16)(xa.x * sa.x); w[1] = (bf16)(xa.y * sa.y);
    w[2] = (bf16)(xa.z * sa.z); w[3] = (bf16)(xa.w * sa.w);
    w[4] = (bf16)(xb.x * sb.x); w[5] = (bf16)(xb.y * sb.y);
    w[6] = (bf16)(xb.z * sb.z); w[7] = (bf16)(xb.w * sb.w);
    return w;
}
__device__ __forceinline__ v8bf cvt8(float4 xa, float4 xb) {
    v8bf w;
    w[0] = (bf16)xa.x; w[1] = (bf16)xa.y; w[2] = (bf16)xa.z; w[3] = (bf16)xa.w;
    w[4] = (bf16)xb.x; w[5] = (bf16)xb.y; w[6] = (bf16)xb.z; w[7] = (bf16)xb.w;
    return w;
}

// ---------------- prep: transposed, zero-padded bf16 weights + padded f32 biases ----------------
__global__ __launch_bounds__(256) void prep_kernel(
    const float* __restrict__ pw1, const float* __restrict__ pw2,
    const float* __restrict__ aw1, const float* __restrict__ aw2,
    const float* __restrict__ mw1, const float* __restrict__ mw2,
    const float* __restrict__ pb1, const float* __restrict__ pb2, const float* __restrict__ pw3,
    const float* __restrict__ ab1, const float* __restrict__ ab2, const float* __restrict__ aw3,
    const float* __restrict__ mb1, const float* __restrict__ mb2, const float* __restrict__ mw3,
    bf16* __restrict__ w1cT, bf16* __restrict__ w2pT,
    bf16* __restrict__ w1aT, bf16* __restrict__ w2aT, bf16* __restrict__ w2mT,
    bf16* __restrict__ wuvmT, float* __restrict__ bias)
{
    int idx = blockIdx.x * 256 + threadIdx.x;
    if (idx < 147456) {                                   // w1cT[h][e] <- pw1[(1536+e)*150+h]
        int h = idx / 768, e = idx % 768;
        w1cT[idx] = (bf16)((h < 150) ? pw1[(1536 + e) * 150 + h] : 0.f);
    } else if (idx < 178176) {                            // w2pT[n][k] <- pw2[k*150+n]
        int j = idx - 147456; int n = j / 160, k = j % 160;
        w2pT[j] = (bf16)((n < 150 && k < 150) ? pw2[k * 150 + n] : 0.f);
    } else if (idx < 227328) {                            // w1aT[h][e] <- aw1[e*150+h]
        int j = idx - 178176; int h = j / 256, e = j % 256;
        w1aT[j] = (bf16)((h < 150) ? aw1[e * 150 + h] : 0.f);
    } else if (idx < 258048) {                            // w2aT[n][k] <- aw2[k*150+n]
        int j = idx - 227328; int n = j / 160, k = j % 160;
        w2aT[j] = (bf16)((n < 150 && k < 150) ? aw2[k * 150 + n] : 0.f);
    } else if (idx < 288768) {                            // w2mT[n][k] <- mw2[k*150+n]
        int j = idx - 258048; int n = j / 160, k = j % 160;
        w2mT[j] = (bf16)((n < 150 && k < 150) ? mw2[k * 150 + n] : 0.f);
    } else if (idx < 731136) {                            // wuvmT[s][h][e]
        int j = idx - 288768; int s = j / 147456; int r = j % 147456;
        int h = r / 768, e = r % 768;
        float v = 0.f;
        if (h < 150) {
            if (s == 0)      v = pw1[e * 150 + h];
            else if (s == 1) v = pw1[(768 + e) * 150 + h];
            else             v = mw1[e * 150 + h];
        }
        wuvmT[j] = (bf16)v;
    } else if (idx < 732864) {                            // 9 padded f32 bias arrays
        int j = idx - 731136; int arr = j / 192, h = j % 192;
        const float* src;
        switch (arr) {
            case 0: src = pb1; break; case 1: src = pb2; break; case 2: src = pw3; break;
            case 3: src = ab1; break; case 4: src = ab2; break; case 5: src = aw3; break;
            case 6: src = mb1; break; case 7: src = mb2; break; default: src = mw3; break;
        }
        bias[j] = (h < 150) ? src[h] : 0.f;
    }
}

// ---------------- build g = [start, end, weighted] ----------------
__global__ __launch_bounds__(256) void build_g_kernel(
    const float* __restrict__ emb, const int* __restrict__ spans,
    const float* __restrict__ attns, float* __restrict__ g)
{
    int blk = blockIdx.x;
    int b = blk >> 7;
    int t0 = spans[blk];
    int e = threadIdx.x;
    const float* eb = emb + ((size_t)(b * 2048 + t0)) * 256 + e;
    const float* at = attns + b * 2048 + t0;
    float start = eb[0];
    float endv  = eb[7 * 256];
    float wsum = 0.f;
#pragma unroll
    for (int w = 0; w < 8; ++w) wsum = fmaf(eb[w * 256], at[w], wsum);
    g[(size_t)blk * 768 + e]       = start;
    g[(size_t)blk * 768 + 256 + e] = endv;
    g[(size_t)blk * 768 + 512 + e] = wsum;
}

// ---------------- attn MLP via MFMA: 32 blocks, M=128, K=256, N=192pad ----------------
__global__ __launch_bounds__(512) void attn_mfma_kernel(
    const float* __restrict__ emb,
    const bf16* __restrict__ w1aT, const bf16* __restrict__ w2aT,
    const float* __restrict__ b1p, const float* __restrict__ b2p,
    const float* __restrict__ w3p, const float* __restrict__ b3,
    float* __restrict__ attns)
{
    __shared__ __attribute__((aligned(16))) char smem[109568];
    bf16*  a_lds  = (bf16*)smem;
    bf16*  b_lds  = (bf16*)(smem + 36864);
    bf16*  h1_lds = (bf16*)smem;
    bf16*  w2_lds = (bf16*)(smem + 43008);
    float* red    = (float*)(smem + 107520);

    const int m0  = blockIdx.x * 128;
    const int tid = threadIdx.x;
    const int lane = tid & 63;
    const int wm = (tid >> 6) >> 2, wn = (tid >> 6) & 3;
    const int l15 = lane & 15, lk = (lane >> 4) * 8;
    const int aj = tid >> 2, ae = (tid & 3) * 16;
    const int bn = tid >> 1, bk = (tid & 1) * 32;

    {   // prologue: chunk 0
        const float* gs = emb + (size_t)(m0 + aj) * 256 + ae;
        float4 x0 = *(const float4*)(gs + 0),  x1 = *(const float4*)(gs + 4);
        float4 x2 = *(const float4*)(gs + 8),  x3 = *(const float4*)(gs + 12);
        bf16* ad = a_lds + aj * 72 + ae;
        *(v8bf*)ad       = cvt8(x0, x1);
        *(v8bf*)(ad + 8) = cvt8(x2, x3);
        if (tid < 384) {
            const bf16* bs = w1aT + bn * 256 + bk;
            bf16* bd = b_lds + bn * 72 + bk;
#pragma unroll
            for (int c2 = 0; c2 < 4; ++c2)
                *(uint4*)(bd + c2 * 8) = *(const uint4*)(bs + c2 * 8);
        }
    }
    __syncthreads();

    v4f acc[4][3];
#pragma unroll
    for (int mf = 0; mf < 4; ++mf)
#pragma unroll
        for (int nf = 0; nf < 3; ++nf) acc[mf][nf] = (v4f){0.f, 0.f, 0.f, 0.f};

    int cur = 0;
    for (int c = 0; c < 4; ++c) {
        float4 x0, x1, x2, x3;
        uint4 bv0, bv1, bv2, bv3;
        if (c < 3) {
            const int e0 = (c + 1) * 64;
            const float* gs = emb + (size_t)(m0 + aj) * 256 + e0 + ae;
            x0 = *(const float4*)(gs + 0);  x1 = *(const float4*)(gs + 4);
            x2 = *(const float4*)(gs + 8);  x3 = *(const float4*)(gs + 12);
            if (tid < 384) {
                const bf16* bs = w1aT + bn * 256 + e0 + bk;
                bv0 = *(const uint4*)(bs + 0);  bv1 = *(const uint4*)(bs + 8);
                bv2 = *(const uint4*)(bs + 16); bv3 = *(const uint4*)(bs + 24);
            }
        }
        const bf16* ab = a_lds + cur * 9216;
        const bf16* bb = b_lds + cur * 13824;
#pragma unroll
        for (int ks = 0; ks < 2; ++ks) {
            const int kb = ks * 32 + lk;
            v8s af[4], bfr[3];
#pragma unroll
            for (int mf = 0; mf < 4; ++mf)
                af[mf] = *(const v8s*)&ab[(wm * 64 + mf * 16 + l15) * 72 + kb];
#pragma unroll
            for (int nf = 0; nf < 3; ++nf)
                bfr[nf] = *(const v8s*)&bb[(wn * 48 + nf * 16 + l15) * 72 + kb];
#pragma unroll
            for (int mf = 0; mf < 4; ++mf)
#pragma unroll
                for (int nf = 0; nf < 3; ++nf)
                    acc[mf][nf] = MFMA_BF16(af[mf], bfr[nf], acc[mf][nf]);
        }
        if (c < 3) {
            bf16* ad = a_lds + (cur ^ 1) * 9216 + aj * 72 + ae;
            *(v8bf*)ad       = cvt8(x0, x1);
            *(v8bf*)(ad + 8) = cvt8(x2, x3);
            if (tid < 384) {
                bf16* bd = b_lds + (cur ^ 1) * 13824 + bn * 72 + bk;
                *(uint4*)(bd + 0)  = bv0; *(uint4*)(bd + 8)  = bv1;
                *(uint4*)(bd + 16) = bv2; *(uint4*)(bd + 24) = bv3;
            }
        }
        __syncthreads();
        cur ^= 1;
    }

    if (tid < 384) {   // stage W2a^T
        const int n = tid >> 1, kh = (tid & 1) * 80;
        const bf16* src = w2aT + n * 160 + kh;
        bf16* dst = w2_lds + n * 168 + kh;
#pragma unroll
        for (int c2 = 0; c2 < 10; ++c2)
            *(uint4*)(dst + c2 * 8) = *(const uint4*)(src + c2 * 8);
    }

    {   // layer1 epilogue: h1 = relu(acc + b1)
        const float b10 = b1p[wn * 48 + 0  + l15];
        const float b11 = b1p[wn * 48 + 16 + l15];
        const float b12 = b1p[wn * 48 + 32 + l15];
#pragma unroll
        for (int mf = 0; mf < 4; ++mf) {
#pragma unroll
            for (int r = 0; r < 4; ++r) {
                const int j = wm * 64 + mf * 16 + (lane >> 4) * 4 + r;
                bf16* hrow = h1_lds + j * 168 + wn * 48 + l15;
                hrow[0] = (bf16)fmaxf(acc[mf][0][r] + b10, 0.f);
                if (wn < 3) {
                    hrow[16] = (bf16)fmaxf(acc[mf][1][r] + b11, 0.f);
                    hrow[32] = (bf16)fmaxf(acc[mf][2][r] + b12, 0.f);
                }
            }
        }
    }
    __syncthreads();

    v4f acc2[4][3];
#pragma unroll
    for (int mf = 0; mf < 4; ++mf)
#pragma unroll
        for (int nf = 0; nf < 3; ++nf) acc2[mf][nf] = (v4f){0.f, 0.f, 0.f, 0.f};
#pragma unroll
    for (int ks = 0; ks < 5; ++ks) {
        const int kb = ks * 32 + lk;
        v8s af[4], bfr[3];
#pragma unroll
        for (int mf = 0; mf < 4; ++mf)
            af[mf] = *(const v8s*)&h1_lds[(wm * 64 + mf * 16 + l15) * 168 + kb];
#pragma unroll
        for (int nf = 0; nf < 3; ++nf)
            bfr[nf] = *(const v8s*)&w2_lds[(wn * 48 + nf * 16 + l15) * 168 + kb];
#pragma unroll
        for (int mf = 0; mf < 4; ++mf)
#pragma unroll
            for (int nf = 0; nf < 3; ++nf)
                acc2[mf][nf] = MFMA_BF16(af[mf], bfr[nf], acc2[mf][nf]);
    }

    const float b2v0 = b2p[wn * 48 + 0  + l15], w3v0 = w3p[wn * 48 + 0  + l15];
    const float b2v1 = b2p[wn * 48 + 16 + l15], w3v1 = w3p[wn * 48 + 16 + l15];
    const float b2v2 = b2p[wn * 48 + 32 + l15], w3v2 = w3p[wn * 48 + 32 + l15];
#pragma unroll
    for (int mf = 0; mf < 4; ++mf) {
#pragma unroll
        for (int r = 0; r < 4; ++r) {
            float p = fmaxf(acc2[mf][0][r] + b2v0, 0.f) * w3v0
                    + fmaxf(acc2[mf][1][r] + b2v1, 0.f) * w3v1
                    + fmaxf(acc2[mf][2][r] + b2v2, 0.f) * w3v2;
            p += __shfl_xor(p, 1);
            p += __shfl_xor(p, 2);
            p += __shfl_xor(p, 4);
            p += __shfl_xor(p, 8);
            if (l15 == 0) {
                const int j = wm * 64 + mf * 16 + (lane >> 4) * 4 + r;
                red[j * 4 + wn] = p;
            }
        }
    }
    __syncthreads();
    if (tid < 128) {
        attns[m0 + tid] = red[tid * 4 + 0] + red[tid * 4 + 1]
                        + red[tid * 4 + 2] + red[tid * 4 + 3] + b3[0];
    }
}

// ---------------- uvm via MFMA: 6 blocks = 2 row-tiles x 3 sections (u,v,ment) ----------------
__global__ __launch_bounds__(512) void uvm_mfma_kernel(
    const float* __restrict__ g, const bf16* __restrict__ wuvmT,
    const bf16* __restrict__ w2mT,
    const float* __restrict__ pb1p, const float* __restrict__ mb1p,
    const float* __restrict__ mb2p, const float* __restrict__ mw3p,
    const float* __restrict__ mb3,
    float* __restrict__ u_pad, float* __restrict__ v_pad, float* __restrict__ ment)
{
    __shared__ __attribute__((aligned(16))) char smem[109568];
    bf16*  a_lds  = (bf16*)smem;
    bf16*  b_lds  = (bf16*)(smem + 36864);
    bf16*  h1_lds = (bf16*)smem;
    bf16*  w2_lds = (bf16*)(smem + 43008);
    float* red    = (float*)(smem + 107520);

    const int sect = blockIdx.x >> 1;          // 0=u, 1=v, 2=ment
    const int m0   = (blockIdx.x & 1) * 128;
    const bf16* Bw = wuvmT + (size_t)sect * 147456;
    const int tid = threadIdx.x;
    const int lane = tid & 63;
    const int wm = (tid >> 6) >> 2, wn = (tid >> 6) & 3;
    const int l15 = lane & 15, lk = (lane >> 4) * 8;
    const int aj = tid >> 2, ae = (tid & 3) * 16;
    const int bn = tid >> 1, bk = (tid & 1) * 32;

    {   // prologue
        const float* gs = g + (size_t)(m0 + aj) * 768 + ae;
        float4 x0 = *(const float4*)(gs + 0),  x1 = *(const float4*)(gs + 4);
        float4 x2 = *(const float4*)(gs + 8),  x3 = *(const float4*)(gs + 12);
        bf16* ad = a_lds + aj * 72 + ae;
        *(v8bf*)ad       = cvt8(x0, x1);
        *(v8bf*)(ad + 8) = cvt8(x2, x3);
        if (tid < 384) {
            const bf16* bs = Bw + bn * 768 + bk;
            bf16* bd = b_lds + bn * 72 + bk;
#pragma unroll
            for (int c2 = 0; c2 < 4; ++c2)
                *(uint4*)(bd + c2 * 8) = *(const uint4*)(bs + c2 * 8);
        }
    }
    __syncthreads();

    v4f acc[4][3];
#pragma unroll
    for (int mf = 0; mf < 4; ++mf)
#pragma unroll
        for (int nf = 0; nf < 3; ++nf) acc[mf][nf] = (v4f){0.f, 0.f, 0.f, 0.f};

    int cur = 0;
    for (int c = 0; c < 12; ++c) {
        float4 x0, x1, x2, x3;
        uint4 bv0, bv1, bv2, bv3;
        if (c < 11) {
            const int e0 = (c + 1) * 64;
            const float* gs = g + (size_t)(m0 + aj) * 768 + e0 + ae;
            x0 = *(const float4*)(gs + 0);  x1 = *(const float4*)(gs + 4);
            x2 = *(const float4*)(gs + 8);  x3 = *(const float4*)(gs + 12);
            if (tid < 384) {
                const bf16* bs = Bw + bn * 768 + e0 + bk;
                bv0 = *(const uint4*)(bs + 0);  bv1 = *(const uint4*)(bs + 8);
                bv2 = *(const uint4*)(bs + 16); bv3 = *(const uint4*)(bs + 24);
            }
        }
        const bf16* ab = a_lds + cur * 9216;
        const bf16* bb = b_lds + cur * 13824;
#pragma unroll
        for (int ks = 0; ks < 2; ++ks) {
            const int kb = ks * 32 + lk;
            v8s af[4], bfr[3];
#pragma unroll
            for (int mf = 0; mf < 4; ++mf)
                af[mf] = *(const v8s*)&ab[(wm * 64 + mf * 16 + l15) * 72 + kb];
#pragma unroll
            for (int nf = 0; nf < 3; ++nf)
                bfr[nf] = *(const v8s*)&bb[(wn * 48 + nf * 16 + l15) * 72 + kb];
#pragma unroll
            for (int mf = 0; mf < 4; ++mf)
#pragma unroll
                for (int nf = 0; nf < 3; ++nf)
                    acc[mf][nf] = MFMA_BF16(af[mf], bfr[nf], acc[mf][nf]);
        }
        if (c < 11) {
            bf16* ad = a_lds + (cur ^ 1) * 9216 + aj * 72 + ae;
            *(v8bf*)ad       = cvt8(x0, x1);
            *(v8bf*)(ad + 8) = cvt8(x2, x3);
            if (tid < 384) {
                bf16* bd = b_lds + (cur ^ 1) * 13824 + bn * 72 + bk;
                *(uint4*)(bd + 0)  = bv0; *(uint4*)(bd + 8)  = bv1;
                *(uint4*)(bd + 16) = bv2; *(uint4*)(bd + 24) = bv3;
            }
        }
        __syncthreads();
        cur ^= 1;
    }

    if (sect < 2) {
        // store u_pad / v_pad (f32), bias pb1 only for u; pad cols hold zeros
        float* dst = (sect == 0) ? u_pad : v_pad;
        const float bb0 = (sect == 0) ? pb1p[wn * 48 + 0  + l15] : 0.f;
        const float bb1 = (sect == 0) ? pb1p[wn * 48 + 16 + l15] : 0.f;
        const float bb2 = (sect == 0) ? pb1p[wn * 48 + 32 + l15] : 0.f;
#pragma unroll
        for (int mf = 0; mf < 4; ++mf) {
#pragma unroll
            for (int r = 0; r < 4; ++r) {
                const int j = wm * 64 + mf * 16 + (lane >> 4) * 4 + r;
                float* drow = dst + (size_t)(m0 + j) * 192 + wn * 48 + l15;
                drow[0]  = acc[mf][0][r] + bb0;
                drow[16] = acc[mf][1][r] + bb1;
                drow[32] = acc[mf][2][r] + bb2;
            }
        }
        return;
    }

    // ---- ment tail ----
    if (tid < 384) {
        const int n = tid >> 1, kh = (tid & 1) * 80;
        const bf16* src = w2mT + n * 160 + kh;
        bf16* dst = w2_lds + n * 168 + kh;
#pragma unroll
        for (int c2 = 0; c2 < 10; ++c2)
            *(uint4*)(dst + c2 * 8) = *(const uint4*)(src + c2 * 8);
    }
    {
        const float b10 = mb1p[wn * 48 + 0  + l15];
        const float b11 = mb1p[wn * 48 + 16 + l15];
        const float b12 = mb1p[wn * 48 + 32 + l15];
#pragma unroll
        for (int mf = 0; mf < 4; ++mf) {
#pragma unroll
            for (int r = 0; r < 4; ++r) {
                const int j = wm * 64 + mf * 16 + (lane >> 4) * 4 + r;
                bf16* hrow = h1_lds + j * 168 + wn * 48 + l15;
                hrow[0] = (bf16)fmaxf(acc[mf][0][r] + b10, 0.f);
                if (wn < 3) {
                    hrow[16] = (bf16)fmaxf(acc[mf][1][r] + b11, 0.f);
                    hrow[32] = (bf16)fmaxf(acc[mf][2][r] + b12, 0.f);
                }
            }
        }
    }
    __syncthreads();

    v4f acc2[4][3];
#pragma unroll
    for (int mf = 0; mf < 4; ++mf)
#pragma unroll
        for (int nf = 0; nf < 3; ++nf) acc2[mf][nf] = (v4f){0.f, 0.f, 0.f, 0.f};
#pragma unroll
    for (int ks = 0; ks < 5; ++ks) {
        const int kb = ks * 32 + lk;
        v8s af[4], bfr[3];
#pragma unroll
        for (int mf = 0; mf < 4; ++mf)
            af[mf] = *(const v8s*)&h1_lds[(wm * 64 + mf * 16 + l15) * 168 + kb];
#pragma unroll
        for (int nf = 0; nf < 3; ++nf)
            bfr[nf] = *(const v8s*)&w2_lds[(wn * 48 + nf * 16 + l15) * 168 + kb];
#pragma unroll
        for (int mf = 0; mf < 4; ++mf)
#pragma unroll
            for (int nf = 0; nf < 3; ++nf)
                acc2[mf][nf] = MFMA_BF16(af[mf], bfr[nf], acc2[mf][nf]);
    }

    const float b2v0 = mb2p[wn * 48 + 0  + l15], w3v0 = mw3p[wn * 48 + 0  + l15];
    const float b2v1 = mb2p[wn * 48 + 16 + l15], w3v1 = mw3p[wn * 48 + 16 + l15];
    const float b2v2 = mb2p[wn * 48 + 32 + l15], w3v2 = mw3p[wn * 48 + 32 + l15];
#pragma unroll
    for (int mf = 0; mf < 4; ++mf) {
#pragma unroll
        for (int r = 0; r < 4; ++r) {
            float p = fmaxf(acc2[mf][0][r] + b2v0, 0.f) * w3v0
                    + fmaxf(acc2[mf][1][r] + b2v1, 0.f) * w3v1
                    + fmaxf(acc2[mf][2][r] + b2v2, 0.f) * w3v2;
            p += __shfl_xor(p, 1);
            p += __shfl_xor(p, 2);
            p += __shfl_xor(p, 4);
            p += __shfl_xor(p, 8);
            if (l15 == 0) {
                const int j = wm * 64 + mf * 16 + (lane >> 4) * 4 + r;
                red[j * 4 + wn] = p;
            }
        }
    }
    __syncthreads();
    if (tid < 128) {
        ment[m0 + tid] = red[tid * 4 + 0] + red[tid * 4 + 1]
                       + red[tid * 4 + 2] + red[tid * 4 + 3] + mb3[0];
    }
}

// ---------------- pair kernel (round-2 verified) ----------------
__global__ __launch_bounds__(512) void pair_mfma_kernel(
    const float* __restrict__ g,
    const float* __restrict__ u_pad, const float* __restrict__ v_pad,
    const bf16* __restrict__ w1cT, const bf16* __restrict__ w2T,
    const float* __restrict__ b2_pad, const float* __restrict__ w3_pad,
    const float* __restrict__ pb3, const float* __restrict__ ment,
    float* __restrict__ out)
{
    __shared__ __attribute__((aligned(16))) char smem[109568];
    bf16*  a_lds  = (bf16*)smem;
    bf16*  b_lds  = (bf16*)(smem + 36864);
    float* gi_s   = (float*)(smem + 92160);
    bf16*  h1_lds = (bf16*)smem;
    bf16*  w2_lds = (bf16*)(smem + 43008);
    float* red    = (float*)(smem + 107520);

    const int blk   = blockIdx.x;
    const int b     = blk >> 7;
    const int row_i = blk;
    const int tid   = threadIdx.x;
    const int lane  = tid & 63;
    const int wm    = (tid >> 6) >> 2;
    const int wn    = (tid >> 6) & 3;
    const int l15   = lane & 15;
    const int lk    = (lane >> 4) * 8;
    const int aj = tid >> 2, ae = (tid & 3) * 16;
    const int bn = tid >> 1, bk = (tid & 1) * 32;

    if (tid < 192)
        *(float4*)&gi_s[tid * 4] = *(const float4*)&g[(size_t)row_i * 768 + tid * 4];
    __syncthreads();

    {
        const float* gs = g + (size_t)(b * 128 + aj) * 768 + ae;
        float4 x0 = *(const float4*)(gs + 0),  x1 = *(const float4*)(gs + 4);
        float4 x2 = *(const float4*)(gs + 8),  x3 = *(const float4*)(gs + 12);
        const float* gp = gi_s + ae;
        float4 s0 = *(const float4*)(gp + 0),  s1 = *(const float4*)(gp + 4);
        float4 s2 = *(const float4*)(gp + 8),  s3 = *(const float4*)(gp + 12);
        bf16* ad = a_lds + aj * 72 + ae;
        *(v8bf*)ad       = mul_cvt8(x0, x1, s0, s1);
        *(v8bf*)(ad + 8) = mul_cvt8(x2, x3, s2, s3);
        if (tid < 384) {
            const bf16* bs = w1cT + bn * 768 + bk;
            bf16* bd = b_lds + bn * 72 + bk;
#pragma unroll
            for (int c2 = 0; c2 < 4; ++c2)
                *(uint4*)(bd + c2 * 8) = *(const uint4*)(bs + c2 * 8);
        }
    }
    __syncthreads();

    v4f acc[4][3];
#pragma unroll
    for (int mf = 0; mf < 4; ++mf)
#pragma unroll
        for (int nf = 0; nf < 3; ++nf) acc[mf][nf] = (v4f){0.f, 0.f, 0.f, 0.f};

    int cur = 0;
    for (int c = 0; c < 12; ++c) {
        float4 x0, x1, x2, x3;
        uint4 bv0, bv1, bv2, bv3;
        if (c < 11) {
            const int e0 = (c + 1) * 64;
            const float* gs = g + (size_t)(b * 128 + aj) * 768 + e0 + ae;
            x0 = *(const float4*)(gs + 0);  x1 = *(const float4*)(gs + 4);
            x2 = *(const float4*)(gs + 8);  x3 = *(const float4*)(gs + 12);
            if (tid < 384) {
                const bf16* bs = w1cT + bn * 768 + e0 + bk;
                bv0 = *(const uint4*)(bs + 0);  bv1 = *(const uint4*)(bs + 8);
                bv2 = *(const uint4*)(bs + 16); bv3 = *(const uint4*)(bs + 24);
            }
        }
        const bf16* ab = a_lds + cur * 9216;
        const bf16* bb = b_lds + cur * 13824;
#pragma unroll
        for (int ks = 0; ks < 2; ++ks) {
            const int kb = ks * 32 + lk;
            v8s af[4], bfr[3];
#pragma unroll
            for (int mf = 0; mf < 4; ++mf)
                af[mf] = *(const v8s*)&ab[(wm * 64 + mf * 16 + l15) * 72 + kb];
#pragma unroll
            for (int nf = 0; nf < 3; ++nf)
                bfr[nf] = *(const v8s*)&bb[(wn * 48 + nf * 16 + l15) * 72 + kb];
#pragma unroll
            for (int mf = 0; mf < 4; ++mf)
#pragma unroll
                for (int nf = 0; nf < 3; ++nf)
                    acc[mf][nf] = MFMA_BF16(af[mf], bfr[nf], acc[mf][nf]);
        }
        if (c < 11) {
            const float* gp = gi_s + (c + 1) * 64 + ae;
            float4 s0 = *(const float4*)(gp + 0),  s1 = *(const float4*)(gp + 4);
            float4 s2 = *(const float4*)(gp + 8),  s3 = *(const float4*)(gp + 12);
            bf16* ad = a_lds + (cur ^ 1) * 9216 + aj * 72 + ae;
            *(v8bf*)ad       = mul_cvt8(x0, x1, s0, s1);
            *(v8bf*)(ad + 8) = mul_cvt8(x2, x3, s2, s3);
            if (tid < 384) {
                bf16* bd = b_lds + (cur ^ 1) * 13824 + bn * 72 + bk;
                *(uint4*)(bd + 0)  = bv0; *(uint4*)(bd + 8)  = bv1;
                *(uint4*)(bd + 16) = bv2; *(uint4*)(bd + 24) = bv3;
            }
        }
        __syncthreads();
        cur ^= 1;
    }

    if (tid < 384) {
        const int n = tid >> 1, kh = (tid & 1) * 80;
        const bf16* src = w2T + n * 160 + kh;
        bf16* dst = w2_lds + n * 168 + kh;
#pragma unroll
        for (int c2 = 0; c2 < 10; ++c2)
            *(uint4*)(dst + c2 * 8) = *(const uint4*)(src + c2 * 8);
    }

    {
        const float uh0 = u_pad[row_i * 192 + wn * 48 + 0  + l15];
        const float uh1 = u_pad[row_i * 192 + wn * 48 + 16 + l15];
        const float uh2 = u_pad[row_i * 192 + wn * 48 + 32 + l15];
#pragma unroll
        for (int mf = 0; mf < 4; ++mf) {
#pragma unroll
            for (int r = 0; r < 4; ++r) {
                const int j = wm * 64 + mf * 16 + (lane >> 4) * 4 + r;
                const float* vrow = v_pad + (size_t)(b * 128 + j) * 192 + wn * 48 + l15;
                const float v0 = acc[mf][0][r] + uh0 + vrow[0];
                const float v1 = acc[mf][1][r] + uh1 + vrow[16];
                const float v2 = acc[mf][2][r] + uh2 + vrow[32];
                bf16* hrow = h1_lds + j * 168 + wn * 48 + l15;
                hrow[0] = (bf16)fmaxf(v0, 0.f);
                if (wn < 3) {
                    hrow[16] = (bf16)fmaxf(v1, 0.f);
                    hrow[32] = (bf16)fmaxf(v2, 0.f);
                }
            }
        }
    }
    __syncthreads();

    v4f acc2[4][3];
#pragma unroll
    for (int mf = 0; mf < 4; ++mf)
#pragma unroll
        for (int nf = 0; nf < 3; ++nf) acc2[mf][nf] = (v4f){0.f, 0.f, 0.f, 0.f};
#pragma unroll
    for (int ks = 0; ks < 5; ++ks) {
        const int kb = ks * 32 + lk;
        v8s af[4], bfr[3];
#pragma unroll
        for (int mf = 0; mf < 4; ++mf)
            af[mf] = *(const v8s*)&h1_lds[(wm * 64 + mf * 16 + l15) * 168 + kb];
#pragma unroll
        for (int nf = 0; nf < 3; ++nf)
            bfr[nf] = *(const v8s*)&w2_lds[(wn * 48 + nf * 16 + l15) * 168 + kb];
#pragma unroll
        for (int mf = 0; mf < 4; ++mf)
#pragma unroll
            for (int nf = 0; nf < 3; ++nf)
                acc2[mf][nf] = MFMA_BF16(af[mf], bfr[nf], acc2[mf][nf]);
    }

    const float b2v0 = b2_pad[wn * 48 + 0  + l15], w3v0 = w3_pad[wn * 48 + 0  + l15];
    const float b2v1 = b2_pad[wn * 48 + 16 + l15], w3v1 = w3_pad[wn * 48 + 16 + l15];
    const float b2v2 = b2_pad[wn * 48 + 32 + l15], w3v2 = w3_pad[wn * 48 + 32 + l15];
#pragma unroll
    for (int mf = 0; mf < 4; ++mf) {
#pragma unroll
        for (int r = 0; r < 4; ++r) {
            float p = fmaxf(acc2[mf][0][r] + b2v0, 0.f) * w3v0
                    + fmaxf(acc2[mf][1][r] + b2v1, 0.f) * w3v1
                    + fmaxf(acc2[mf][2][r] + b2v2, 0.f) * w3v2;
            p += __shfl_xor(p, 1);
            p += __shfl_xor(p, 2);
            p += __shfl_xor(p, 4);
            p += __shfl_xor(p, 8);
            if (l15 == 0) {
                const int j = wm * 64 + mf * 16 + (lane >> 4) * 4 + r;
                red[j * 4 + wn] = p;
            }
        }
    }
    __syncthreads();
    if (tid < 128) {
        const float s = red[tid * 4 + 0] + red[tid * 4 + 1] + red[tid * 4 + 2] + red[tid * 4 + 3];
        out[(size_t)blk * 128 + tid] =
            (s + pb3[0] + ment[row_i] + ment[b * 128 + tid]) * (1.f / 3.f);
    }
}

extern "C" void kernel_launch(void* const* d_in, const int* in_sizes, int n_in,
                              void* d_out, int out_size, void* d_ws, size_t ws_size,
                              hipStream_t stream)
{
    const float* emb   = (const float*)d_in[0];
    const int*   spans = (const int*)d_in[1];
    const float* aw1 = (const float*)d_in[2];
    const float* ab1 = (const float*)d_in[3];
    const float* aw2 = (const float*)d_in[4];
    const float* ab2 = (const float*)d_in[5];
    const float* aw3 = (const float*)d_in[6];
    const float* ab3 = (const float*)d_in[7];
    const float* mw1 = (const float*)d_in[8];
    const float* mb1 = (const float*)d_in[9];
    const float* mw2 = (const float*)d_in[10];
    const float* mb2 = (const float*)d_in[11];
    const float* mw3 = (const float*)d_in[12];
    const float* mb3 = (const float*)d_in[13];
    const float* pw1 = (const float*)d_in[14];
    const float* pb1 = (const float*)d_in[15];
    const float* pw2 = (const float*)d_in[16];
    const float* pb2 = (const float*)d_in[17];
    const float* pw3 = (const float*)d_in[18];
    const float* pb3 = (const float*)d_in[19];

    float* ws    = (float*)d_ws;
    float* attns = ws;              // 4096
    float* g     = ws + 4096;       // 196608
    float* ment  = ws + 200704;     // 256
    float* u_pad = ws + 200960;     // 49152
    float* v_pad = ws + 250112;     // 49152
    float* bias  = ws + 299264;     // 1728
    float* pb1p = bias;         float* pb2p = bias + 192;  float* pw3p = bias + 384;
    float* ab1p = bias + 576;   float* ab2p = bias + 768;  float* aw3p = bias + 960;
    float* mb1p = bias + 1152;  float* mb2p = bias + 1344; float* mw3p = bias + 1536;
    bf16* w1cT  = (bf16*)(ws + 300992);
    bf16* w2pT  = (bf16*)(ws + 374720);
    bf16* w1aT  = (bf16*)(ws + 390080);
    bf16* w2aT  = (bf16*)(ws + 414656);
    bf16* w2mT  = (bf16*)(ws + 430016);
    bf16* wuvmT = (bf16*)(ws + 445376);

    prep_kernel<<<2863, 256, 0, stream>>>(pw1, pw2, aw1, aw2, mw1, mw2,
                                          pb1, pb2, pw3, ab1, ab2, aw3, mb1, mb2, mw3,
                                          w1cT, w2pT, w1aT, w2aT, w2mT, wuvmT, bias);
    attn_mfma_kernel<<<32, 512, 0, stream>>>(emb, w1aT, w2aT, ab1p, ab2p, aw3p, ab3, attns);
    build_g_kernel<<<256, 256, 0, stream>>>(emb, spans, attns, g);
    uvm_mfma_kernel<<<6, 512, 0, stream>>>(g, wuvmT, w2mT, pb1p, mb1p, mb2p, mw3p, mb3,
                                           u_pad, v_pad, ment);
    pair_mfma_kernel<<<256, 512, 0, stream>>>(g, u_pad, v_pad, w1cT, w2pT,
                                              pb2p, pw3p, pb3, ment, (float*)d_out);
}

// Round 4
// 65.623 us; speedup vs baseline: 4.2933x; 1.2405x over previous
//
#include <hip/hip_runtime.h>
#include <hip/hip_bf16.h>

// Problem: B=2, T=2048, E=256, S=128, W=8, H=150
// pairs@w1 = gi@w1a + gj@w1b + (gi*gj)@w1c
// All MLP GEMMs on MFMA (bf16 in, f32 acc). Round-4 change: M-tile 64
// everywhere -> LDS 76.8KB -> 2 blocks/CU; layer-2 B operand (w2*T) read as
// fragments directly from L2 (no LDS staging).
//
// ws layout (float units):
//   attns   [4096]            @ 0
//   g       [196608]          @ 4096
//   ment    [256]             @ 200704
//   u_pad   [49152]           @ 200960
//   v_pad   [49152]           @ 250112
//   bias    [1728 = 9*192]    @ 299264
//   w1cT    bf16[192][768]    @ 300992
//   w2pT    bf16[192][160]    @ 374720
//   w1aT    bf16[192][256]    @ 390080
//   w2aT    bf16[192][160]    @ 414656
//   w2mT    bf16[192][160]    @ 430016
//   wuvmT   bf16[3][192][768] @ 445376
// end @ 666560 floats = 2.67 MB

typedef __bf16 bf16;
typedef __attribute__((ext_vector_type(8))) short v8s;
typedef __attribute__((ext_vector_type(8))) __bf16 v8bf;
typedef __attribute__((ext_vector_type(4))) float v4f;

#define MFMA_BF16(A, B, C) __builtin_amdgcn_mfma_f32_16x16x32_bf16((A), (B), (C), 0, 0, 0)

__device__ __forceinline__ v8bf mul_cvt8(float4 xa, float4 xb, float4 sa, float4 sb) {
    v8bf w;
    w[0] = (bf16)(xa.x * sa.x); w[1] = (bf16)(xa.y * sa.y);
    w[2] = (bf16)(xa.z * sa.z); w[3] = (bf16)(xa.w * sa.w);
    w[4] = (bf16)(xb.x * sb.x); w[5] = (bf16)(xb.y * sb.y);
    w[6] = (bf16)(xb.z * sb.z); w[7] = (bf16)(xb.w * sb.w);
    return w;
}
__device__ __forceinline__ v8bf cvt8(float4 xa, float4 xb) {
    v8bf w;
    w[0] = (bf16)xa.x; w[1] = (bf16)xa.y; w[2] = (bf16)xa.z; w[3] = (bf16)xa.w;
    w[4] = (bf16)xb.x; w[5] = (bf16)xb.y; w[6] = (bf16)xb.z; w[7] = (bf16)xb.w;
    return w;
}

// ---------------- prep: transposed, zero-padded bf16 weights + padded f32 biases ----------------
__global__ __launch_bounds__(256) void prep_kernel(
    const float* __restrict__ pw1, const float* __restrict__ pw2,
    const float* __restrict__ aw1, const float* __restrict__ aw2,
    const float* __restrict__ mw1, const float* __restrict__ mw2,
    const float* __restrict__ pb1, const float* __restrict__ pb2, const float* __restrict__ pw3,
    const float* __restrict__ ab1, const float* __restrict__ ab2, const float* __restrict__ aw3,
    const float* __restrict__ mb1, const float* __restrict__ mb2, const float* __restrict__ mw3,
    bf16* __restrict__ w1cT, bf16* __restrict__ w2pT,
    bf16* __restrict__ w1aT, bf16* __restrict__ w2aT, bf16* __restrict__ w2mT,
    bf16* __restrict__ wuvmT, float* __restrict__ bias)
{
    int idx = blockIdx.x * 256 + threadIdx.x;
    if (idx < 147456) {                                   // w1cT[h][e] <- pw1[(1536+e)*150+h]
        int h = idx / 768, e = idx % 768;
        w1cT[idx] = (bf16)((h < 150) ? pw1[(1536 + e) * 150 + h] : 0.f);
    } else if (idx < 178176) {                            // w2pT[n][k] <- pw2[k*150+n]
        int j = idx - 147456; int n = j / 160, k = j % 160;
        w2pT[j] = (bf16)((n < 150 && k < 150) ? pw2[k * 150 + n] : 0.f);
    } else if (idx < 227328) {                            // w1aT[h][e] <- aw1[e*150+h]
        int j = idx - 178176; int h = j / 256, e = j % 256;
        w1aT[j] = (bf16)((h < 150) ? aw1[e * 150 + h] : 0.f);
    } else if (idx < 258048) {                            // w2aT[n][k] <- aw2[k*150+n]
        int j = idx - 227328; int n = j / 160, k = j % 160;
        w2aT[j] = (bf16)((n < 150 && k < 150) ? aw2[k * 150 + n] : 0.f);
    } else if (idx < 288768) {                            // w2mT[n][k] <- mw2[k*150+n]
        int j = idx - 258048; int n = j / 160, k = j % 160;
        w2mT[j] = (bf16)((n < 150 && k < 150) ? mw2[k * 150 + n] : 0.f);
    } else if (idx < 731136) {                            // wuvmT[s][h][e]
        int j = idx - 288768; int s = j / 147456; int r = j % 147456;
        int h = r / 768, e = r % 768;
        float v = 0.f;
        if (h < 150) {
            if (s == 0)      v = pw1[e * 150 + h];
            else if (s == 1) v = pw1[(768 + e) * 150 + h];
            else             v = mw1[e * 150 + h];
        }
        wuvmT[j] = (bf16)v;
    } else if (idx < 732864) {
        int j = idx - 731136; int arr = j / 192, h = j % 192;
        const float* src;
        switch (arr) {
            case 0: src = pb1; break; case 1: src = pb2; break; case 2: src = pw3; break;
            case 3: src = ab1; break; case 4: src = ab2; break; case 5: src = aw3; break;
            case 6: src = mb1; break; case 7: src = mb2; break; default: src = mw3; break;
        }
        bias[j] = (h < 150) ? src[h] : 0.f;
    }
}

// ---------------- build g = [start, end, weighted] ----------------
__global__ __launch_bounds__(256) void build_g_kernel(
    const float* __restrict__ emb, const int* __restrict__ spans,
    const float* __restrict__ attns, float* __restrict__ g)
{
    int blk = blockIdx.x;
    int b = blk >> 7;
    int t0 = spans[blk];
    int e = threadIdx.x;
    const float* eb = emb + ((size_t)(b * 2048 + t0)) * 256 + e;
    const float* at = attns + b * 2048 + t0;
    float start = eb[0];
    float endv  = eb[7 * 256];
    float wsum = 0.f;
#pragma unroll
    for (int w = 0; w < 8; ++w) wsum = fmaf(eb[w * 256], at[w], wsum);
    g[(size_t)blk * 768 + e]       = start;
    g[(size_t)blk * 768 + 256 + e] = endv;
    g[(size_t)blk * 768 + 512 + e] = wsum;
}

// LDS plan shared by the three MFMA kernels (bytes):
//  phase1: a_lds [2][64][72]bf16 @0 (18432) | b_lds [2][192][72]bf16 @18432 (55296)
//          | gi_s[768]f32 @73728 (3072)  -> 76800 total => 2 blocks/CU
//  phase2 overlay: h1 [64][168]bf16 @0 (21504) | red [64][4]f32 @22528 (1024)
#define SMEM_BYTES 76800
#define A_ELEMS 4608     // 64*72
#define B_ELEMS 13824    // 192*72

// ---------------- attn MLP via MFMA: 64 blocks, M=64, K=256, N=192pad ----------------
__global__ __launch_bounds__(512) void attn_mfma_kernel(
    const float* __restrict__ emb,
    const bf16* __restrict__ w1aT, const bf16* __restrict__ w2aT,
    const float* __restrict__ b1p, const float* __restrict__ b2p,
    const float* __restrict__ w3p, const float* __restrict__ b3,
    float* __restrict__ attns)
{
    __shared__ __attribute__((aligned(16))) char smem[SMEM_BYTES];
    bf16*  a_lds  = (bf16*)smem;
    bf16*  b_lds  = (bf16*)(smem + 18432);
    bf16*  h1_lds = (bf16*)smem;
    float* red    = (float*)(smem + 22528);

    const int m0  = blockIdx.x * 64;
    const int tid = threadIdx.x;
    const int lane = tid & 63;
    const int wm = (tid >> 6) >> 2, wn = (tid >> 6) & 3;
    const int l15 = lane & 15, lk = (lane >> 4) * 8;
    const int aj = tid >> 3, ae = (tid & 7) * 8;
    const int bn = tid >> 1, bk = (tid & 1) * 32;

    {   // prologue: chunk 0
        const float* gs = emb + (size_t)(m0 + aj) * 256 + ae;
        float4 x0 = *(const float4*)(gs + 0), x1 = *(const float4*)(gs + 4);
        *(v8bf*)(a_lds + aj * 72 + ae) = cvt8(x0, x1);
        if (tid < 384) {
            const bf16* bs = w1aT + bn * 256 + bk;
            bf16* bd = b_lds + bn * 72 + bk;
#pragma unroll
            for (int c2 = 0; c2 < 4; ++c2)
                *(uint4*)(bd + c2 * 8) = *(const uint4*)(bs + c2 * 8);
        }
    }
    __syncthreads();

    v4f acc[2][3];
#pragma unroll
    for (int mf = 0; mf < 2; ++mf)
#pragma unroll
        for (int nf = 0; nf < 3; ++nf) acc[mf][nf] = (v4f){0.f, 0.f, 0.f, 0.f};

    int cur = 0;
    for (int c = 0; c < 4; ++c) {
        float4 x0, x1;
        uint4 bv0, bv1, bv2, bv3;
        if (c < 3) {
            const int e0 = (c + 1) * 64;
            const float* gs = emb + (size_t)(m0 + aj) * 256 + e0 + ae;
            x0 = *(const float4*)(gs + 0); x1 = *(const float4*)(gs + 4);
            if (tid < 384) {
                const bf16* bs = w1aT + bn * 256 + e0 + bk;
                bv0 = *(const uint4*)(bs + 0);  bv1 = *(const uint4*)(bs + 8);
                bv2 = *(const uint4*)(bs + 16); bv3 = *(const uint4*)(bs + 24);
            }
        }
        const bf16* ab = a_lds + cur * A_ELEMS;
        const bf16* bb = b_lds + cur * B_ELEMS;
#pragma unroll
        for (int ks = 0; ks < 2; ++ks) {
            const int kb = ks * 32 + lk;
            v8s af[2], bfr[3];
#pragma unroll
            for (int mf = 0; mf < 2; ++mf)
                af[mf] = *(const v8s*)&ab[(wm * 32 + mf * 16 + l15) * 72 + kb];
#pragma unroll
            for (int nf = 0; nf < 3; ++nf)
                bfr[nf] = *(const v8s*)&bb[(wn * 48 + nf * 16 + l15) * 72 + kb];
#pragma unroll
            for (int mf = 0; mf < 2; ++mf)
#pragma unroll
                for (int nf = 0; nf < 3; ++nf)
                    acc[mf][nf] = MFMA_BF16(af[mf], bfr[nf], acc[mf][nf]);
        }
        if (c < 3) {
            *(v8bf*)(a_lds + (cur ^ 1) * A_ELEMS + aj * 72 + ae) = cvt8(x0, x1);
            if (tid < 384) {
                bf16* bd = b_lds + (cur ^ 1) * B_ELEMS + bn * 72 + bk;
                *(uint4*)(bd + 0)  = bv0; *(uint4*)(bd + 8)  = bv1;
                *(uint4*)(bd + 16) = bv2; *(uint4*)(bd + 24) = bv3;
            }
        }
        __syncthreads();
        cur ^= 1;
    }

    {   // layer1 epilogue -> h1 (bf16)
        const float b10 = b1p[wn * 48 + 0  + l15];
        const float b11 = b1p[wn * 48 + 16 + l15];
        const float b12 = b1p[wn * 48 + 32 + l15];
#pragma unroll
        for (int mf = 0; mf < 2; ++mf) {
#pragma unroll
            for (int r = 0; r < 4; ++r) {
                const int jl = wm * 32 + mf * 16 + (lane >> 4) * 4 + r;
                bf16* hrow = h1_lds + jl * 168 + wn * 48 + l15;
                hrow[0] = (bf16)fmaxf(acc[mf][0][r] + b10, 0.f);
                if (wn < 3) {
                    hrow[16] = (bf16)fmaxf(acc[mf][1][r] + b11, 0.f);
                    hrow[32] = (bf16)fmaxf(acc[mf][2][r] + b12, 0.f);
                }
            }
        }
    }
    __syncthreads();

    // layer 2: B fragments straight from global (L2-resident w2aT)
    v4f acc2[2][3];
#pragma unroll
    for (int mf = 0; mf < 2; ++mf)
#pragma unroll
        for (int nf = 0; nf < 3; ++nf) acc2[mf][nf] = (v4f){0.f, 0.f, 0.f, 0.f};
#pragma unroll
    for (int ks = 0; ks < 5; ++ks) {
        const int kb = ks * 32 + lk;
        v8s af[2], bfr[3];
#pragma unroll
        for (int mf = 0; mf < 2; ++mf)
            af[mf] = *(const v8s*)&h1_lds[(wm * 32 + mf * 16 + l15) * 168 + kb];
#pragma unroll
        for (int nf = 0; nf < 3; ++nf)
            bfr[nf] = *(const v8s*)&w2aT[(size_t)(wn * 48 + nf * 16 + l15) * 160 + kb];
#pragma unroll
        for (int mf = 0; mf < 2; ++mf)
#pragma unroll
            for (int nf = 0; nf < 3; ++nf)
                acc2[mf][nf] = MFMA_BF16(af[mf], bfr[nf], acc2[mf][nf]);
    }

    const float b2v0 = b2p[wn * 48 + 0  + l15], w3v0 = w3p[wn * 48 + 0  + l15];
    const float b2v1 = b2p[wn * 48 + 16 + l15], w3v1 = w3p[wn * 48 + 16 + l15];
    const float b2v2 = b2p[wn * 48 + 32 + l15], w3v2 = w3p[wn * 48 + 32 + l15];
#pragma unroll
    for (int mf = 0; mf < 2; ++mf) {
#pragma unroll
        for (int r = 0; r < 4; ++r) {
            float p = fmaxf(acc2[mf][0][r] + b2v0, 0.f) * w3v0
                    + fmaxf(acc2[mf][1][r] + b2v1, 0.f) * w3v1
                    + fmaxf(acc2[mf][2][r] + b2v2, 0.f) * w3v2;
            p += __shfl_xor(p, 1);
            p += __shfl_xor(p, 2);
            p += __shfl_xor(p, 4);
            p += __shfl_xor(p, 8);
            if (l15 == 0) {
                const int jl = wm * 32 + mf * 16 + (lane >> 4) * 4 + r;
                red[jl * 4 + wn] = p;
            }
        }
    }
    __syncthreads();
    if (tid < 64) {
        attns[m0 + tid] = red[tid * 4 + 0] + red[tid * 4 + 1]
                        + red[tid * 4 + 2] + red[tid * 4 + 3] + b3[0];
    }
}

// ---------------- uvm via MFMA: 12 blocks = 3 sections x 4 M-tiles of 64 ----------------
__global__ __launch_bounds__(512) void uvm_mfma_kernel(
    const float* __restrict__ g, const bf16* __restrict__ wuvmT,
    const bf16* __restrict__ w2mT,
    const float* __restrict__ pb1p, const float* __restrict__ mb1p,
    const float* __restrict__ mb2p, const float* __restrict__ mw3p,
    const float* __restrict__ mb3,
    float* __restrict__ u_pad, float* __restrict__ v_pad, float* __restrict__ ment)
{
    __shared__ __attribute__((aligned(16))) char smem[SMEM_BYTES];
    bf16*  a_lds  = (bf16*)smem;
    bf16*  b_lds  = (bf16*)(smem + 18432);
    bf16*  h1_lds = (bf16*)smem;
    float* red    = (float*)(smem + 22528);

    const int sect = blockIdx.x >> 2;          // 0=u, 1=v, 2=ment
    const int m0   = (blockIdx.x & 3) * 64;
    const bf16* Bw = wuvmT + (size_t)sect * 147456;
    const int tid = threadIdx.x;
    const int lane = tid & 63;
    const int wm = (tid >> 6) >> 2, wn = (tid >> 6) & 3;
    const int l15 = lane & 15, lk = (lane >> 4) * 8;
    const int aj = tid >> 3, ae = (tid & 7) * 8;
    const int bn = tid >> 1, bk = (tid & 1) * 32;

    {   // prologue
        const float* gs = g + (size_t)(m0 + aj) * 768 + ae;
        float4 x0 = *(const float4*)(gs + 0), x1 = *(const float4*)(gs + 4);
        *(v8bf*)(a_lds + aj * 72 + ae) = cvt8(x0, x1);
        if (tid < 384) {
            const bf16* bs = Bw + bn * 768 + bk;
            bf16* bd = b_lds + bn * 72 + bk;
#pragma unroll
            for (int c2 = 0; c2 < 4; ++c2)
                *(uint4*)(bd + c2 * 8) = *(const uint4*)(bs + c2 * 8);
        }
    }
    __syncthreads();

    v4f acc[2][3];
#pragma unroll
    for (int mf = 0; mf < 2; ++mf)
#pragma unroll
        for (int nf = 0; nf < 3; ++nf) acc[mf][nf] = (v4f){0.f, 0.f, 0.f, 0.f};

    int cur = 0;
    for (int c = 0; c < 12; ++c) {
        float4 x0, x1;
        uint4 bv0, bv1, bv2, bv3;
        if (c < 11) {
            const int e0 = (c + 1) * 64;
            const float* gs = g + (size_t)(m0 + aj) * 768 + e0 + ae;
            x0 = *(const float4*)(gs + 0); x1 = *(const float4*)(gs + 4);
            if (tid < 384) {
                const bf16* bs = Bw + bn * 768 + e0 + bk;
                bv0 = *(const uint4*)(bs + 0);  bv1 = *(const uint4*)(bs + 8);
                bv2 = *(const uint4*)(bs + 16); bv3 = *(const uint4*)(bs + 24);
            }
        }
        const bf16* ab = a_lds + cur * A_ELEMS;
        const bf16* bb = b_lds + cur * B_ELEMS;
#pragma unroll
        for (int ks = 0; ks < 2; ++ks) {
            const int kb = ks * 32 + lk;
            v8s af[2], bfr[3];
#pragma unroll
            for (int mf = 0; mf < 2; ++mf)
                af[mf] = *(const v8s*)&ab[(wm * 32 + mf * 16 + l15) * 72 + kb];
#pragma unroll
            for (int nf = 0; nf < 3; ++nf)
                bfr[nf] = *(const v8s*)&bb[(wn * 48 + nf * 16 + l15) * 72 + kb];
#pragma unroll
            for (int mf = 0; mf < 2; ++mf)
#pragma unroll
                for (int nf = 0; nf < 3; ++nf)
                    acc[mf][nf] = MFMA_BF16(af[mf], bfr[nf], acc[mf][nf]);
        }
        if (c < 11) {
            *(v8bf*)(a_lds + (cur ^ 1) * A_ELEMS + aj * 72 + ae) = cvt8(x0, x1);
            if (tid < 384) {
                bf16* bd = b_lds + (cur ^ 1) * B_ELEMS + bn * 72 + bk;
                *(uint4*)(bd + 0)  = bv0; *(uint4*)(bd + 8)  = bv1;
                *(uint4*)(bd + 16) = bv2; *(uint4*)(bd + 24) = bv3;
            }
        }
        __syncthreads();
        cur ^= 1;
    }

    if (sect < 2) {
        float* dst = (sect == 0) ? u_pad : v_pad;
        const float bb0 = (sect == 0) ? pb1p[wn * 48 + 0  + l15] : 0.f;
        const float bb1 = (sect == 0) ? pb1p[wn * 48 + 16 + l15] : 0.f;
        const float bb2 = (sect == 0) ? pb1p[wn * 48 + 32 + l15] : 0.f;
#pragma unroll
        for (int mf = 0; mf < 2; ++mf) {
#pragma unroll
            for (int r = 0; r < 4; ++r) {
                const int jl = wm * 32 + mf * 16 + (lane >> 4) * 4 + r;
                float* drow = dst + (size_t)(m0 + jl) * 192 + wn * 48 + l15;
                drow[0]  = acc[mf][0][r] + bb0;
                drow[16] = acc[mf][1][r] + bb1;
                drow[32] = acc[mf][2][r] + bb2;
            }
        }
        return;
    }

    // ---- ment tail ----
    {
        const float b10 = mb1p[wn * 48 + 0  + l15];
        const float b11 = mb1p[wn * 48 + 16 + l15];
        const float b12 = mb1p[wn * 48 + 32 + l15];
#pragma unroll
        for (int mf = 0; mf < 2; ++mf) {
#pragma unroll
            for (int r = 0; r < 4; ++r) {
                const int jl = wm * 32 + mf * 16 + (lane >> 4) * 4 + r;
                bf16* hrow = h1_lds + jl * 168 + wn * 48 + l15;
                hrow[0] = (bf16)fmaxf(acc[mf][0][r] + b10, 0.f);
                if (wn < 3) {
                    hrow[16] = (bf16)fmaxf(acc[mf][1][r] + b11, 0.f);
                    hrow[32] = (bf16)fmaxf(acc[mf][2][r] + b12, 0.f);
                }
            }
        }
    }
    __syncthreads();

    v4f acc2[2][3];
#pragma unroll
    for (int mf = 0; mf < 2; ++mf)
#pragma unroll
        for (int nf = 0; nf < 3; ++nf) acc2[mf][nf] = (v4f){0.f, 0.f, 0.f, 0.f};
#pragma unroll
    for (int ks = 0; ks < 5; ++ks) {
        const int kb = ks * 32 + lk;
        v8s af[2], bfr[3];
#pragma unroll
        for (int mf = 0; mf < 2; ++mf)
            af[mf] = *(const v8s*)&h1_lds[(wm * 32 + mf * 16 + l15) * 168 + kb];
#pragma unroll
        for (int nf = 0; nf < 3; ++nf)
            bfr[nf] = *(const v8s*)&w2mT[(size_t)(wn * 48 + nf * 16 + l15) * 160 + kb];
#pragma unroll
        for (int mf = 0; mf < 2; ++mf)
#pragma unroll
            for (int nf = 0; nf < 3; ++nf)
                acc2[mf][nf] = MFMA_BF16(af[mf], bfr[nf], acc2[mf][nf]);
    }

    const float b2v0 = mb2p[wn * 48 + 0  + l15], w3v0 = mw3p[wn * 48 + 0  + l15];
    const float b2v1 = mb2p[wn * 48 + 16 + l15], w3v1 = mw3p[wn * 48 + 16 + l15];
    const float b2v2 = mb2p[wn * 48 + 32 + l15], w3v2 = mw3p[wn * 48 + 32 + l15];
#pragma unroll
    for (int mf = 0; mf < 2; ++mf) {
#pragma unroll
        for (int r = 0; r < 4; ++r) {
            float p = fmaxf(acc2[mf][0][r] + b2v0, 0.f) * w3v0
                    + fmaxf(acc2[mf][1][r] + b2v1, 0.f) * w3v1
                    + fmaxf(acc2[mf][2][r] + b2v2, 0.f) * w3v2;
            p += __shfl_xor(p, 1);
            p += __shfl_xor(p, 2);
            p += __shfl_xor(p, 4);
            p += __shfl_xor(p, 8);
            if (l15 == 0) {
                const int jl = wm * 32 + mf * 16 + (lane >> 4) * 4 + r;
                red[jl * 4 + wn] = p;
            }
        }
    }
    __syncthreads();
    if (tid < 64) {
        ment[m0 + tid] = red[tid * 4 + 0] + red[tid * 4 + 1]
                       + red[tid * 4 + 2] + red[tid * 4 + 3] + mb3[0];
    }
}

// ---------------- pair kernel: 512 blocks = (b, i, j-half), M=64 ----------------
__global__ __launch_bounds__(512) void pair_mfma_kernel(
    const float* __restrict__ g,
    const float* __restrict__ u_pad, const float* __restrict__ v_pad,
    const bf16* __restrict__ w1cT, const bf16* __restrict__ w2T,
    const float* __restrict__ b2_pad, const float* __restrict__ w3_pad,
    const float* __restrict__ pb3, const float* __restrict__ ment,
    float* __restrict__ out)
{
    __shared__ __attribute__((aligned(16))) char smem[SMEM_BYTES];
    bf16*  a_lds  = (bf16*)smem;
    bf16*  b_lds  = (bf16*)(smem + 18432);
    float* gi_s   = (float*)(smem + 73728);
    bf16*  h1_lds = (bf16*)smem;
    float* red    = (float*)(smem + 22528);

    const int blk   = blockIdx.x;          // b*256 + i*2 + half
    const int b     = blk >> 8;
    const int i     = (blk >> 1) & 127;
    const int half  = blk & 1;
    const int row_i = b * 128 + i;
    const int jg0   = b * 128 + half * 64;  // global row base of this j-half
    const int tid   = threadIdx.x;
    const int lane  = tid & 63;
    const int wm = (tid >> 6) >> 2, wn = (tid >> 6) & 3;
    const int l15 = lane & 15, lk = (lane >> 4) * 8;
    const int aj = tid >> 3, ae = (tid & 7) * 8;
    const int bn = tid >> 1, bk = (tid & 1) * 32;

    if (tid < 192)
        *(float4*)&gi_s[tid * 4] = *(const float4*)&g[(size_t)row_i * 768 + tid * 4];
    __syncthreads();

    {   // prologue: chunk 0
        const float* gs = g + (size_t)(jg0 + aj) * 768 + ae;
        float4 x0 = *(const float4*)(gs + 0), x1 = *(const float4*)(gs + 4);
        const float* gp = gi_s + ae;
        float4 s0 = *(const float4*)(gp + 0), s1 = *(const float4*)(gp + 4);
        *(v8bf*)(a_lds + aj * 72 + ae) = mul_cvt8(x0, x1, s0, s1);
        if (tid < 384) {
            const bf16* bs = w1cT + bn * 768 + bk;
            bf16* bd = b_lds + bn * 72 + bk;
#pragma unroll
            for (int c2 = 0; c2 < 4; ++c2)
                *(uint4*)(bd + c2 * 8) = *(const uint4*)(bs + c2 * 8);
        }
    }
    __syncthreads();

    v4f acc[2][3];
#pragma unroll
    for (int mf = 0; mf < 2; ++mf)
#pragma unroll
        for (int nf = 0; nf < 3; ++nf) acc[mf][nf] = (v4f){0.f, 0.f, 0.f, 0.f};

    int cur = 0;
    for (int c = 0; c < 12; ++c) {
        float4 x0, x1;
        uint4 bv0, bv1, bv2, bv3;
        if (c < 11) {
            const int e0 = (c + 1) * 64;
            const float* gs = g + (size_t)(jg0 + aj) * 768 + e0 + ae;
            x0 = *(const float4*)(gs + 0); x1 = *(const float4*)(gs + 4);
            if (tid < 384) {
                const bf16* bs = w1cT + bn * 768 + e0 + bk;
                bv0 = *(const uint4*)(bs + 0);  bv1 = *(const uint4*)(bs + 8);
                bv2 = *(const uint4*)(bs + 16); bv3 = *(const uint4*)(bs + 24);
            }
        }
        const bf16* ab = a_lds + cur * A_ELEMS;
        const bf16* bb = b_lds + cur * B_ELEMS;
#pragma unroll
        for (int ks = 0; ks < 2; ++ks) {
            const int kb = ks * 32 + lk;
            v8s af[2], bfr[3];
#pragma unroll
            for (int mf = 0; mf < 2; ++mf)
                af[mf] = *(const v8s*)&ab[(wm * 32 + mf * 16 + l15) * 72 + kb];
#pragma unroll
            for (int nf = 0; nf < 3; ++nf)
                bfr[nf] = *(const v8s*)&bb[(wn * 48 + nf * 16 + l15) * 72 + kb];
#pragma unroll
            for (int mf = 0; mf < 2; ++mf)
#pragma unroll
                for (int nf = 0; nf < 3; ++nf)
                    acc[mf][nf] = MFMA_BF16(af[mf], bfr[nf], acc[mf][nf]);
        }
        if (c < 11) {
            const float* gp = gi_s + (c + 1) * 64 + ae;
            float4 s0 = *(const float4*)(gp + 0), s1 = *(const float4*)(gp + 4);
            *(v8bf*)(a_lds + (cur ^ 1) * A_ELEMS + aj * 72 + ae) = mul_cvt8(x0, x1, s0, s1);
            if (tid < 384) {
                bf16* bd = b_lds + (cur ^ 1) * B_ELEMS + bn * 72 + bk;
                *(uint4*)(bd + 0)  = bv0; *(uint4*)(bd + 8)  = bv1;
                *(uint4*)(bd + 16) = bv2; *(uint4*)(bd + 24) = bv3;
            }
        }
        __syncthreads();
        cur ^= 1;
    }

    {   // layer1 epilogue: h1 = relu(cross + u_i + v_j)
        const float uh0 = u_pad[row_i * 192 + wn * 48 + 0  + l15];
        const float uh1 = u_pad[row_i * 192 + wn * 48 + 16 + l15];
        const float uh2 = u_pad[row_i * 192 + wn * 48 + 32 + l15];
#pragma unroll
        for (int mf = 0; mf < 2; ++mf) {
#pragma unroll
            for (int r = 0; r < 4; ++r) {
                const int jl = wm * 32 + mf * 16 + (lane >> 4) * 4 + r;
                const float* vrow = v_pad + (size_t)(jg0 + jl) * 192 + wn * 48 + l15;
                const float v0 = acc[mf][0][r] + uh0 + vrow[0];
                const float v1 = acc[mf][1][r] + uh1 + vrow[16];
                const float v2 = acc[mf][2][r] + uh2 + vrow[32];
                bf16* hrow = h1_lds + jl * 168 + wn * 48 + l15;
                hrow[0] = (bf16)fmaxf(v0, 0.f);
                if (wn < 3) {
                    hrow[16] = (bf16)fmaxf(v1, 0.f);
                    hrow[32] = (bf16)fmaxf(v2, 0.f);
                }
            }
        }
    }
    __syncthreads();

    v4f acc2[2][3];
#pragma unroll
    for (int mf = 0; mf < 2; ++mf)
#pragma unroll
        for (int nf = 0; nf < 3; ++nf) acc2[mf][nf] = (v4f){0.f, 0.f, 0.f, 0.f};
#pragma unroll
    for (int ks = 0; ks < 5; ++ks) {
        const int kb = ks * 32 + lk;
        v8s af[2], bfr[3];
#pragma unroll
        for (int mf = 0; mf < 2; ++mf)
            af[mf] = *(const v8s*)&h1_lds[(wm * 32 + mf * 16 + l15) * 168 + kb];
#pragma unroll
        for (int nf = 0; nf < 3; ++nf)
            bfr[nf] = *(const v8s*)&w2T[(size_t)(wn * 48 + nf * 16 + l15) * 160 + kb];
#pragma unroll
        for (int mf = 0; mf < 2; ++mf)
#pragma unroll
            for (int nf = 0; nf < 3; ++nf)
                acc2[mf][nf] = MFMA_BF16(af[mf], bfr[nf], acc2[mf][nf]);
    }

    const float b2v0 = b2_pad[wn * 48 + 0  + l15], w3v0 = w3_pad[wn * 48 + 0  + l15];
    const float b2v1 = b2_pad[wn * 48 + 16 + l15], w3v1 = w3_pad[wn * 48 + 16 + l15];
    const float b2v2 = b2_pad[wn * 48 + 32 + l15], w3v2 = w3_pad[wn * 48 + 32 + l15];
#pragma unroll
    for (int mf = 0; mf < 2; ++mf) {
#pragma unroll
        for (int r = 0; r < 4; ++r) {
            float p = fmaxf(acc2[mf][0][r] + b2v0, 0.f) * w3v0
                    + fmaxf(acc2[mf][1][r] + b2v1, 0.f) * w3v1
                    + fmaxf(acc2[mf][2][r] + b2v2, 0.f) * w3v2;
            p += __shfl_xor(p, 1);
            p += __shfl_xor(p, 2);
            p += __shfl_xor(p, 4);
            p += __shfl_xor(p, 8);
            if (l15 == 0) {
                const int jl = wm * 32 + mf * 16 + (lane >> 4) * 4 + r;
                red[jl * 4 + wn] = p;
            }
        }
    }
    __syncthreads();
    if (tid < 64) {
        const float s = red[tid * 4 + 0] + red[tid * 4 + 1] + red[tid * 4 + 2] + red[tid * 4 + 3];
        out[(size_t)b * 16384 + (size_t)i * 128 + half * 64 + tid] =
            (s + pb3[0] + ment[row_i] + ment[b * 128 + half * 64 + tid]) * (1.f / 3.f);
    }
}

extern "C" void kernel_launch(void* const* d_in, const int* in_sizes, int n_in,
                              void* d_out, int out_size, void* d_ws, size_t ws_size,
                              hipStream_t stream)
{
    const float* emb   = (const float*)d_in[0];
    const int*   spans = (const int*)d_in[1];
    const float* aw1 = (const float*)d_in[2];
    const float* ab1 = (const float*)d_in[3];
    const float* aw2 = (const float*)d_in[4];
    const float* ab2 = (const float*)d_in[5];
    const float* aw3 = (const float*)d_in[6];
    const float* ab3 = (const float*)d_in[7];
    const float* mw1 = (const float*)d_in[8];
    const float* mb1 = (const float*)d_in[9];
    const float* mw2 = (const float*)d_in[10];
    const float* mb2 = (const float*)d_in[11];
    const float* mw3 = (const float*)d_in[12];
    const float* mb3 = (const float*)d_in[13];
    const float* pw1 = (const float*)d_in[14];
    const float* pb1 = (const float*)d_in[15];
    const float* pw2 = (const float*)d_in[16];
    const float* pb2 = (const float*)d_in[17];
    const float* pw3 = (const float*)d_in[18];
    const float* pb3 = (const float*)d_in[19];

    float* ws    = (float*)d_ws;
    float* attns = ws;              // 4096
    float* g     = ws + 4096;       // 196608
    float* ment  = ws + 200704;     // 256
    float* u_pad = ws + 200960;     // 49152
    float* v_pad = ws + 250112;     // 49152
    float* bias  = ws + 299264;     // 1728
    float* pb1p = bias;         float* pb2p = bias + 192;  float* pw3p = bias + 384;
    float* ab1p = bias + 576;   float* ab2p = bias + 768;  float* aw3p = bias + 960;
    float* mb1p = bias + 1152;  float* mb2p = bias + 1344; float* mw3p = bias + 1536;
    bf16* w1cT  = (bf16*)(ws + 300992);
    bf16* w2pT  = (bf16*)(ws + 374720);
    bf16* w1aT  = (bf16*)(ws + 390080);
    bf16* w2aT  = (bf16*)(ws + 414656);
    bf16* w2mT  = (bf16*)(ws + 430016);
    bf16* wuvmT = (bf16*)(ws + 445376);

    prep_kernel<<<2863, 256, 0, stream>>>(pw1, pw2, aw1, aw2, mw1, mw2,
                                          pb1, pb2, pw3, ab1, ab2, aw3, mb1, mb2, mw3,
                                          w1cT, w2pT, w1aT, w2aT, w2mT, wuvmT, bias);
    attn_mfma_kernel<<<64, 512, 0, stream>>>(emb, w1aT, w2aT, ab1p, ab2p, aw3p, ab3, attns);
    build_g_kernel<<<256, 256, 0, stream>>>(emb, spans, attns, g);
    uvm_mfma_kernel<<<12, 512, 0, stream>>>(g, wuvmT, w2mT, pb1p, mb1p, mb2p, mw3p, mb3,
                                            u_pad, v_pad, ment);
    pair_mfma_kernel<<<512, 512, 0, stream>>>(g, u_pad, v_pad, w1cT, w2pT,
                                              pb2p, pw3p, pb3, ment, (float*)d_out);
}